// Round 7
// baseline (238.307 us; speedup 1.0000x reference)
//
#include <hip/hip_runtime.h>

#define NN 50000
#define NE 800000
#define NBLK 196  // ceil(NN/256)

typedef _Float16 half8 __attribute__((ext_vector_type(8)));
typedef _Float16 half4 __attribute__((ext_vector_type(4)));
typedef float f32x4v __attribute__((ext_vector_type(4)));

// ---------------- CSR build ----------------
__global__ void k_zero(int* __restrict__ deg) {
  int i = blockIdx.x * 256 + threadIdx.x;
  if (i < NN) deg[i] = 0;
}

__global__ void k_hist(const int* __restrict__ dst, int* __restrict__ deg) {
  int e = blockIdx.x * 256 + threadIdx.x;
  if (e < NE) atomicAdd(&deg[dst[e]], 1);
}

__global__ void k_blksum(const int* __restrict__ deg, int* __restrict__ blksum) {
  __shared__ int s[256];
  int n = blockIdx.x * 256 + threadIdx.x;
  s[threadIdx.x] = (n < NN) ? deg[n] : 0;
  __syncthreads();
  for (int off = 128; off > 0; off >>= 1) {
    if (threadIdx.x < off) s[threadIdx.x] += s[threadIdx.x + off];
    __syncthreads();
  }
  if (threadIdx.x == 0) blksum[blockIdx.x] = s[0];
}

__global__ void k_blkscan(const int* __restrict__ blksum, int* __restrict__ blkoff) {
  __shared__ int s[256];
  int t = threadIdx.x;
  int v0 = (t < NBLK) ? blksum[t] : 0;
  s[t] = v0;
  __syncthreads();
  for (int off = 1; off < 256; off <<= 1) {
    int v = (t >= off) ? s[t - off] : 0;
    __syncthreads();
    s[t] += v;
    __syncthreads();
  }
  if (t < NBLK) blkoff[t] = s[t] - v0;  // exclusive
}

__global__ void k_scan3(const int* __restrict__ deg, const int* __restrict__ blkoff,
                        int* __restrict__ row_start, int* __restrict__ cursor,
                        float* __restrict__ dinv, float* __restrict__ rdinv) {
  __shared__ int s[256];
  int n = blockIdx.x * 256 + threadIdx.x;
  int d = (n < NN) ? deg[n] : 0;
  s[threadIdx.x] = d;
  __syncthreads();
  for (int off = 1; off < 256; off <<= 1) {
    int v = (threadIdx.x >= off) ? s[threadIdx.x - off] : 0;
    __syncthreads();
    s[threadIdx.x] += v;
    __syncthreads();
  }
  if (n < NN) {
    int rs = blkoff[blockIdx.x] + s[threadIdx.x] - d;
    row_start[n] = rs;
    cursor[n] = rs;
    float df = (float)d + 2.0f;
    dinv[n] = rsqrtf(df);
    rdinv[n] = sqrtf(df);
  }
  if (n == 0) row_start[NN] = NE;
}

// 4-byte scatter: only src index; coefficients are factored into features.
__global__ void k_scatter(const int* __restrict__ srcv, const int* __restrict__ dstv,
                          int* __restrict__ cursor, int* __restrict__ esrc) {
  int e = blockIdx.x * 256 + threadIdx.x;
  if (e >= NE) return;
  int s = srcv[e], d = dstv[e];
  int pos = atomicAdd(&cursor[d], 1);
  esrc[pos] = s;
}

// ---------------- weight composition (tiny) ----------------
__global__ void k_prep_misc(const float* __restrict__ w2, const float* __restrict__ fw2,
                            const float* __restrict__ w3, const float* __restrict__ fw3,
                            const float* __restrict__ b1, const float* __restrict__ fw1,
                            const float* __restrict__ fb1,
                            const float* __restrict__ b2, const float* __restrict__ fb2,
                            const float* __restrict__ b3, const float* __restrict__ fb3,
                            float* __restrict__ Wc2, float* __restrict__ Wc3,
                            float* __restrict__ bc1, float* __restrict__ bc2,
                            float* __restrict__ bc3) {
  int id = blockIdx.x * 256 + threadIdx.x;
  if (id < 2048) {                       // Wc2 [32,64]
    int c = id >> 6, k = id & 63;
    float s = 0.f;
    for (int j = 0; j < 64; ++j) s = fmaf(w2[c * 64 + j], fw2[j * 64 + k], s);
    Wc2[id] = s;
  } else if (id < 10240) {               // Wc3 [64,128]
    int idx = id - 2048;
    int c = idx >> 7, k = idx & 127;
    float s = 0.f;
    for (int j = 0; j < 128; ++j) s = fmaf(w3[c * 128 + j], fw3[j * 128 + k], s);
    Wc3[idx] = s;
  } else if (id < 10272) {               // bc1 [32]
    int k = id - 10240;
    float s = fb1[k];
    for (int j = 0; j < 32; ++j) s = fmaf(b1[j], fw1[j * 32 + k], s);
    bc1[k] = s;
  } else if (id < 10336) {               // bc2 [64]
    int k = id - 10272;
    float s = fb2[k];
    for (int j = 0; j < 64; ++j) s = fmaf(b2[j], fw2[j * 64 + k], s);
    bc2[k] = s;
  } else if (id < 10464) {               // bc3 [128]
    int k = id - 10336;
    float s = fb3[k];
    for (int j = 0; j < 128; ++j) s = fmaf(b3[j], fw3[j * 128 + k], s);
    bc3[k] = s;
  }
}

__global__ void k_prep_G(const float* __restrict__ wd3, const float* __restrict__ wf,
                         float* __restrict__ G) {
  int id = blockIdx.x * 256 + threadIdx.x;
  if (id >= 16384) return;
  int k = id & 127, r = id >> 7;
  int c = r >> 2, l = r & 3;
  float s = 0.f;
  for (int o = 0; o < 32; ++o) {
    s = fmaf(wd3[c * 64 + o * 2 + 0], wf[(o * 8 + 2 * l + 0) * 128 + k], s);
    s = fmaf(wd3[c * 64 + o * 2 + 1], wf[(o * 8 + 2 * l + 1) * 128 + k], s);
  }
  G[r * 128 + k] = s;
}

__global__ void k_prep_HA1(const float* __restrict__ wd2, const float* __restrict__ G,
                           const float* __restrict__ ws2,
                           float* __restrict__ Hm, float* __restrict__ A1) {
  int id = blockIdx.x * 256 + threadIdx.x;
  if (id < 16384) {
    int k = id & 127, r = id >> 7;
    int c = r >> 1, l = r & 1;
    float s = 0.f;
    for (int o = 0; o < 32; ++o) {
      s = fmaf(wd2[c * 64 + o * 2 + 0], G[(o * 4 + 2 * l + 0) * 128 + k], s);
      s = fmaf(wd2[c * 64 + o * 2 + 1], G[(o * 4 + 2 * l + 1) * 128 + k], s);
    }
    Hm[r * 128 + k] = s;
  } else if (id < 16384 + 4096) {
    int idx = id - 16384;
    int k = idx & 127, c = idx >> 7;   // c < 32
    float s = 0.f;
    for (int o = 0; o < 32; ++o) {
      float g = G[(4 * o) * 128 + k] + G[(4 * o + 1) * 128 + k] +
                G[(4 * o + 2) * 128 + k] + G[(4 * o + 3) * 128 + k];
      s = fmaf(ws2[c * 32 + o], g, s);
    }
    A1[c * 128 + k] = s;
  }
}

__global__ void k_prep_A32c0(const float* __restrict__ wd1, const float* __restrict__ ws1,
                             const float* __restrict__ Hm, const float* __restrict__ G,
                             const float* __restrict__ wf,
                             const float* __restrict__ bd1, const float* __restrict__ bs1,
                             const float* __restrict__ bd2, const float* __restrict__ bs2,
                             const float* __restrict__ bd3, const float* __restrict__ bf,
                             float* __restrict__ A3, float* __restrict__ A2,
                             float* __restrict__ c0) {
  int id = blockIdx.x * 256 + threadIdx.x;
  if (id < 16384) {
    int k = id & 127, c = id >> 7;
    float s = 0.f;
    for (int j = 0; j < 128; ++j) s = fmaf(wd1[c * 128 + j], Hm[j * 128 + k], s);
    A3[c * 128 + k] = s;
  } else if (id < 16384 + 8192) {
    int idx = id - 16384;
    int k = idx & 127, c = idx >> 7;   // c < 64
    float s = 0.f;
    for (int o = 0; o < 64; ++o)
      s = fmaf(ws1[c * 64 + o], Hm[(2 * o) * 128 + k] + Hm[(2 * o + 1) * 128 + k], s);
    A2[c * 128 + k] = s;
  } else if (id < 16384 + 8192 + 128) {
    int k = id - 16384 - 8192;
    float s = bf[k];
    for (int o = 0; o < 64; ++o) {
      float b = bd1[o] + bs1[o];
      s = fmaf(b, Hm[(o * 2) * 128 + k] + Hm[(o * 2 + 1) * 128 + k], s);
    }
    for (int o = 0; o < 32; ++o) {
      float b = bd2[o] + bs2[o];
      float g = G[(o * 4) * 128 + k] + G[(o * 4 + 1) * 128 + k] +
                G[(o * 4 + 2) * 128 + k] + G[(o * 4 + 3) * 128 + k];
      s = fmaf(b, g, s);
    }
    for (int o = 0; o < 32; ++o) {
      float w8 = 0.f;
      for (int j = 0; j < 8; ++j) w8 += wf[(o * 8 + j) * 128 + k];
      s = fmaf(bd3[o], w8, s);
    }
    c0[k] = s;
  }
}

// -------- pack B fragments (f16) for mfma_f32_16x16x32_f16 --------
__global__ void k_prep_pack(const float* __restrict__ Wc3, const float* __restrict__ Acat,
                            _Float16* __restrict__ W3pk, _Float16* __restrict__ Apk) {
  int id = blockIdx.x * 256 + threadIdx.x;
  if (id < 1024) {
    int l = id & 63, nb = (id >> 6) & 7, kb = id >> 9;
    int kbase = kb * 32 + ((l >> 4) << 3);
    int col = nb * 16 + (l & 15);
#pragma unroll
    for (int j = 0; j < 8; ++j)
      W3pk[id * 8 + j] = (_Float16)Wc3[(kbase + j) * 128 + col];
  } else if (id < 1024 + 3584) {
    int idx = id - 1024;
    int l = idx & 63, nb = (idx >> 6) & 7, kb = idx >> 9;
    int kbase = kb * 32 + ((l >> 4) << 3);
    int col = nb * 16 + (l & 15);
#pragma unroll
    for (int j = 0; j < 8; ++j)
      Apk[idx * 8 + j] = (_Float16)Acat[(kbase + j) * 128 + col];
  }
}

// ---------------- layer-1: h1' = dinv[n] * (x @ w1), register-tiled ----------
__launch_bounds__(256)
__global__ void k_gemm1t(const float* __restrict__ X, const float* __restrict__ W,
                         const float* __restrict__ dinv, float* __restrict__ Y) {
  __shared__ float sW[128 * 32];
  __shared__ float sXc[128 * 33];
  int t = threadIdx.x;
  int n0 = blockIdx.x * 128;
#pragma unroll
  for (int it = 0; it < 4; ++it) {
    int idx = t + it * 256;
    int kr = idx >> 3, c4 = (idx & 7) * 4;
    *reinterpret_cast<float4*>(&sW[kr * 32 + c4]) =
        *reinterpret_cast<const float4*>(&W[kr * 32 + c4]);
  }
  int rg = t >> 3;
  int cg = t & 7;
  float acc[4][4];
#pragma unroll
  for (int r = 0; r < 4; ++r)
#pragma unroll
    for (int c = 0; c < 4; ++c) acc[r][c] = 0.f;

  for (int ch = 0; ch < 4; ++ch) {
    __syncthreads();
#pragma unroll
    for (int it = 0; it < 4; ++it) {
      int idx = t + it * 256;
      int row = idx & 127, k4 = (idx >> 7) * 4;
      int n = n0 + row;
      float4 v = make_float4(0.f, 0.f, 0.f, 0.f);
      if (n < NN) v = *reinterpret_cast<const float4*>(&X[(size_t)n * 128 + ch * 32 + k4]);
      sXc[row * 33 + k4 + 0] = v.x;
      sXc[row * 33 + k4 + 1] = v.y;
      sXc[row * 33 + k4 + 2] = v.z;
      sXc[row * 33 + k4 + 3] = v.w;
    }
    __syncthreads();
#pragma unroll
    for (int k = 0; k < 32; ++k) {
      float4 w = *reinterpret_cast<const float4*>(&sW[(ch * 32 + k) * 32 + cg * 4]);
#pragma unroll
      for (int r = 0; r < 4; ++r) {
        float xv = sXc[(rg * 4 + r) * 33 + k];
        acc[r][0] = fmaf(xv, w.x, acc[r][0]);
        acc[r][1] = fmaf(xv, w.y, acc[r][1]);
        acc[r][2] = fmaf(xv, w.z, acc[r][2]);
        acc[r][3] = fmaf(xv, w.w, acc[r][3]);
      }
    }
  }
#pragma unroll
  for (int r = 0; r < 4; ++r) {
    int n = n0 + rg * 4 + r;
    if (n < NN) {
      float dv = dinv[n];
      *reinterpret_cast<float4*>(&Y[(size_t)n * 32 + cg * 4]) =
          make_float4(dv * acc[r][0], dv * acc[r][1], dv * acc[r][2], dv * acc[r][3]);
    }
  }
}

// ---- coef-free 4-way gather sum for F=32 (input pre-scaled by dinv) ----
// S[n] = 2*H'[n] + sum_e H'[src];  32 lanes/node: fg=lane&7, way=(lane>>3)&3
__device__ inline float4 gsum32(const float4* __restrict__ H4,
                                const int* __restrict__ esrc,
                                const int* __restrict__ row_start,
                                int n, int fg, int way) {
  float4 acc = make_float4(0.f, 0.f, 0.f, 0.f);
  if (way == 0) {
    float4 h = H4[(size_t)n * 8 + fg];
    acc.x = 2.f * h.x; acc.y = 2.f * h.y; acc.z = 2.f * h.z; acc.w = 2.f * h.w;
  }
  int end = row_start[n + 1];
  int i = row_start[n] + way;
  for (; i + 4 < end; i += 8) {
    int s0 = esrc[i], s1 = esrc[i + 4];
    float4 a = H4[(size_t)s0 * 8 + fg];
    float4 b = H4[(size_t)s1 * 8 + fg];
    acc.x += a.x; acc.y += a.y; acc.z += a.z; acc.w += a.w;
    acc.x += b.x; acc.y += b.y; acc.z += b.z; acc.w += b.w;
  }
  if (i < end) {
    int s = esrc[i];
    float4 a = H4[(size_t)s * 8 + fg];
    acc.x += a.x; acc.y += a.y; acc.z += a.z; acc.w += a.w;
  }
  acc.x += __shfl_xor(acc.x, 8);  acc.y += __shfl_xor(acc.y, 8);
  acc.z += __shfl_xor(acc.z, 8);  acc.w += __shfl_xor(acc.w, 8);
  acc.x += __shfl_xor(acc.x, 16); acc.y += __shfl_xor(acc.y, 16);
  acc.z += __shfl_xor(acc.z, 16); acc.w += __shfl_xor(acc.w, 16);
  return acc;
}

// ---- fused gather(F=32) + GEMM 32->32 + relu; in/out pre-scaled by dinv ----
__launch_bounds__(256)
__global__ void k_fuse1(const float* __restrict__ H, const int* __restrict__ esrc,
                        const int* __restrict__ row_start, const float* __restrict__ dinv,
                        const float* __restrict__ W, const float* __restrict__ bias,
                        float* __restrict__ Y) {
  __shared__ float sZT[32][9];   // [feat][node], z = dinv*S
  __shared__ float sW[32 * 32];
  int t = threadIdx.x;
  int n0 = blockIdx.x * 8;
  {
    int kr = t >> 3, c4 = (t & 7) * 4;
    *reinterpret_cast<float4*>(&sW[kr * 32 + c4]) =
        *reinterpret_cast<const float4*>(&W[kr * 32 + c4]);
  }
  int node = t >> 5, fg = t & 7, way = (t >> 3) & 3;
  int n = n0 + node;
  float4 z = gsum32(reinterpret_cast<const float4*>(H), esrc, row_start, n, fg, way);
  if (way == 0) {
    float dv = dinv[n];
    sZT[fg * 4 + 0][node] = dv * z.x;
    sZT[fg * 4 + 1][node] = dv * z.y;
    sZT[fg * 4 + 2][node] = dv * z.z;
    sZT[fg * 4 + 3][node] = dv * z.w;
  }
  __syncthreads();
  int nd = t >> 5, col = t & 31;
  float a = bias[col];
#pragma unroll
  for (int k = 0; k < 32; ++k) a = fmaf(sZT[k][nd], sW[k * 32 + col], a);
  Y[(size_t)(n0 + nd) * 32 + col] = dinv[n0 + nd] * fmaxf(a, 0.f);
}

// ---- fused gather(F=32) + GEMM 32->64 + relu; in/out pre-scaled by dinv ----
__launch_bounds__(256)
__global__ void k_fuse2(const float* __restrict__ H, const int* __restrict__ esrc,
                        const int* __restrict__ row_start, const float* __restrict__ dinv,
                        const float* __restrict__ W, const float* __restrict__ bias,
                        float* __restrict__ Y) {
  __shared__ float sZT[32][9];
  __shared__ float sW[32 * 64];
  int t = threadIdx.x;
  int n0 = blockIdx.x * 8;
#pragma unroll
  for (int it = 0; it < 2; ++it) {
    int idx = t + it * 256;
    int kr = idx >> 4, c4 = (idx & 15) * 4;
    *reinterpret_cast<float4*>(&sW[kr * 64 + c4]) =
        *reinterpret_cast<const float4*>(&W[kr * 64 + c4]);
  }
  int node = t >> 5, fg = t & 7, way = (t >> 3) & 3;
  int n = n0 + node;
  float4 z = gsum32(reinterpret_cast<const float4*>(H), esrc, row_start, n, fg, way);
  if (way == 0) {
    float dv = dinv[n];
    sZT[fg * 4 + 0][node] = dv * z.x;
    sZT[fg * 4 + 1][node] = dv * z.y;
    sZT[fg * 4 + 2][node] = dv * z.z;
    sZT[fg * 4 + 3][node] = dv * z.w;
  }
  __syncthreads();
  int nd = t >> 5, col = t & 31;
  float a = bias[col], b = bias[col + 32];
#pragma unroll
  for (int k = 0; k < 32; ++k) {
    float zv = sZT[k][nd];
    a = fmaf(zv, sW[k * 64 + col], a);
    b = fmaf(zv, sW[k * 64 + col + 32], b);
  }
  float dv = dinv[n0 + nd];
  Y[(size_t)(n0 + nd) * 64 + col] = dv * fmaxf(a, 0.f);
  Y[(size_t)(n0 + nd) * 64 + col + 32] = dv * fmaxf(b, 0.f);
}

// ------- coef-free 4-way gather F=64 -> z3 (true scale) as f16 -------
__launch_bounds__(256)
__global__ void k_gath64(const float* __restrict__ H, const int* __restrict__ esrc,
                         const int* __restrict__ row_start, const float* __restrict__ dinv,
                         _Float16* __restrict__ Zh) {
  int t = threadIdx.x;
  int n = blockIdx.x * 4 + (t >> 6);
  int fg = t & 15, way = (t >> 4) & 3;
  const float4* H4 = reinterpret_cast<const float4*>(H);
  float4 acc = make_float4(0.f, 0.f, 0.f, 0.f);
  if (way == 0) {
    float4 h = H4[(size_t)n * 16 + fg];
    acc.x = 2.f * h.x; acc.y = 2.f * h.y; acc.z = 2.f * h.z; acc.w = 2.f * h.w;
  }
  int end = row_start[n + 1];
  int i = row_start[n] + way;
  for (; i + 4 < end; i += 8) {
    int s0 = esrc[i], s1 = esrc[i + 4];
    float4 a = H4[(size_t)s0 * 16 + fg];
    float4 b = H4[(size_t)s1 * 16 + fg];
    acc.x += a.x; acc.y += a.y; acc.z += a.z; acc.w += a.w;
    acc.x += b.x; acc.y += b.y; acc.z += b.z; acc.w += b.w;
  }
  if (i < end) {
    int s = esrc[i];
    float4 a = H4[(size_t)s * 16 + fg];
    acc.x += a.x; acc.y += a.y; acc.z += a.z; acc.w += a.w;
  }
  acc.x += __shfl_xor(acc.x, 16); acc.y += __shfl_xor(acc.y, 16);
  acc.z += __shfl_xor(acc.z, 16); acc.w += __shfl_xor(acc.w, 16);
  acc.x += __shfl_xor(acc.x, 32); acc.y += __shfl_xor(acc.y, 32);
  acc.z += __shfl_xor(acc.z, 32); acc.w += __shfl_xor(acc.w, 32);
  if (way == 0) {
    float dv = dinv[n];
    half4 hv;
    hv[0] = (_Float16)(dv * acc.x); hv[1] = (_Float16)(dv * acc.y);
    hv[2] = (_Float16)(dv * acc.z); hv[3] = (_Float16)(dv * acc.w);
    *reinterpret_cast<half4*>(Zh + (size_t)n * 64 + fg * 4) = hv;
  }
}

// ---- convert 8 f32 -> half8 fragment, with scale ----
__device__ inline half8 cvt8s(const float* __restrict__ p, float s) {
  float4 u = *reinterpret_cast<const float4*>(p);
  float4 v = *reinterpret_cast<const float4*>(p + 4);
  half8 a;
  a[0] = (_Float16)(s * u.x); a[1] = (_Float16)(s * u.y);
  a[2] = (_Float16)(s * u.z); a[3] = (_Float16)(s * u.w);
  a[4] = (_Float16)(s * v.x); a[5] = (_Float16)(s * v.y);
  a[6] = (_Float16)(s * v.z); a[7] = (_Float16)(s * v.w);
  return a;
}

// ------- MFMA decode: x3 = relu(z3@Wc3+bc3); out = c0 + [x3|x2|x1] @ Acat -------
// x2/x1 arrive pre-scaled by dinv; un-scale by rdinv[nrow] during f16 conversion.
__launch_bounds__(256)
__global__ void k_decode(const _Float16* __restrict__ z3h, const float* __restrict__ X2,
                         const float* __restrict__ X1, const float* __restrict__ rdinv,
                         const half8* __restrict__ W3pk, const half8* __restrict__ Apk,
                         const float* __restrict__ bc3, const float* __restrict__ c0,
                         float* __restrict__ out) {
  __shared__ _Float16 sX3[4][16][136];
  int t = threadIdx.x;
  int w = t >> 6, l = t & 63;
  int m16 = l & 15, g = l >> 4;
  int n0 = blockIdx.x * 64 + w * 16;
  int nrow = n0 + m16;

  f32x4v acc[8];
  // ---- Phase B: x3 = relu(z3 @ Wc3 + bc3), K=64 ----
#pragma unroll
  for (int nb = 0; nb < 8; ++nb) {
    float bv = bc3[nb * 16 + m16];
    acc[nb] = (f32x4v){bv, bv, bv, bv};
  }
#pragma unroll
  for (int kb = 0; kb < 2; ++kb) {
    half8 a = *reinterpret_cast<const half8*>(z3h + (size_t)nrow * 64 + kb * 32 + g * 8);
#pragma unroll
    for (int nb = 0; nb < 8; ++nb) {
      half8 b = W3pk[(kb * 8 + nb) * 64 + l];
      acc[nb] = __builtin_amdgcn_mfma_f32_16x16x32_f16(a, b, acc[nb], 0, 0, 0);
    }
  }
#pragma unroll
  for (int nb = 0; nb < 8; ++nb)
#pragma unroll
    for (int r = 0; r < 4; ++r)
      sX3[w][g * 4 + r][nb * 16 + m16] = (_Float16)fmaxf(acc[nb][r], 0.0f);
  __syncthreads();

  // ---- Phase C: out = c0 + [x3|x2|x1] @ Acat, K=224 ----
  float rd = rdinv[nrow];
#pragma unroll
  for (int nb = 0; nb < 8; ++nb) {
    float cv = c0[nb * 16 + m16];
    acc[nb] = (f32x4v){cv, cv, cv, cv};
  }
#pragma unroll
  for (int kb = 0; kb < 7; ++kb) {
    half8 a;
    if (kb < 4)
      a = *reinterpret_cast<const half8*>(&sX3[w][m16][kb * 32 + g * 8]);
    else if (kb < 6)
      a = cvt8s(X2 + (size_t)nrow * 64 + (kb - 4) * 32 + g * 8, rd);
    else
      a = cvt8s(X1 + (size_t)nrow * 32 + g * 8, rd);
#pragma unroll
    for (int nb = 0; nb < 8; ++nb) {
      half8 b = Apk[(kb * 8 + nb) * 64 + l];
      acc[nb] = __builtin_amdgcn_mfma_f32_16x16x32_f16(a, b, acc[nb], 0, 0, 0);
    }
  }
#pragma unroll
  for (int nb = 0; nb < 8; ++nb)
#pragma unroll
    for (int r = 0; r < 4; ++r) {
      int n = n0 + g * 4 + r;
      if (n < NN) out[(size_t)n * 128 + nb * 16 + m16] = acc[nb][r];
    }
}

extern "C" void kernel_launch(void* const* d_in, const int* in_sizes, int n_in,
                              void* d_out, int out_size, void* d_ws, size_t ws_size,
                              hipStream_t stream) {
  const float* x   = (const float*)d_in[0];
  const int* ei    = (const int*)d_in[1];
  const int* srcv  = ei;
  const int* dstv  = ei + NE;
  const float* w1  = (const float*)d_in[2];
  const float* b1  = (const float*)d_in[3];
  const float* fw1 = (const float*)d_in[4];
  const float* fb1 = (const float*)d_in[5];
  const float* w2  = (const float*)d_in[6];
  const float* b2  = (const float*)d_in[7];
  const float* fw2 = (const float*)d_in[8];
  const float* fb2 = (const float*)d_in[9];
  const float* w3  = (const float*)d_in[10];
  const float* b3  = (const float*)d_in[11];
  const float* fw3 = (const float*)d_in[12];
  const float* fb3 = (const float*)d_in[13];
  const float* wd1 = (const float*)d_in[14];
  const float* bd1 = (const float*)d_in[15];
  const float* wd2 = (const float*)d_in[16];
  const float* bd2 = (const float*)d_in[17];
  const float* wd3 = (const float*)d_in[18];
  const float* bd3 = (const float*)d_in[19];
  const float* ws1 = (const float*)d_in[20];
  const float* bs1 = (const float*)d_in[21];
  const float* ws2 = (const float*)d_in[22];
  const float* bs2 = (const float*)d_in[23];
  const float* wf  = (const float*)d_in[24];
  const float* bf  = (const float*)d_in[25];

  float* fp = (float*)d_ws;
  float* dinv = fp;                  // 50176
  float* rdinv= dinv + 50176;        // 50176
  float* h1   = rdinv + 50176;       // 50048*32 f32; later overlaid by z3h (f16)
  float* x1   = h1 + 1601536;        // 50048*32 (pre-scaled by dinv)
  float* x2   = x1 + 1601536;        // 50048*64 (pre-scaled by dinv)
  float* Wc2  = x2 + 3203072;        // 2048
  float* Wc3  = Wc2 + 2048;          // 8192
  float* bc1  = Wc3 + 8192;          // 64
  float* bc2  = bc1 + 64;            // 64
  float* bc3  = bc2 + 64;            // 128
  float* G    = bc3 + 128;           // 16384
  float* Hm   = G + 16384;           // 16384
  float* A3   = Hm + 16384;          // 16384 } Acat = A3|A2|A1 contiguous [224][128]
  float* A2   = A3 + 16384;          // 8192  }
  float* A1   = A2 + 8192;           // 4096  }
  float* c0   = A1 + 4096;           // 256
  _Float16* W3pk = (_Float16*)(c0 + 256);   // 8192 halves
  _Float16* Apk  = W3pk + 8192;             // 28672 halves
  int* ip     = (int*)(Apk + 28672);
  int* esrc   = ip;                  // 800000 int
  int* deg    = esrc + 800000;       // 50176
  int* row_start = deg + 50176;      // 50176 (NN+1 used)
  int* cursor = row_start + 50176;   // 50176
  int* blksum = cursor + 50176;      // 256
  int* blkoff = blksum + 256;        // 256

  _Float16* z3h = (_Float16*)h1;     // overlay: h1 dead after k_fuse1
  float* outp = (float*)d_out;

  // ---- CSR build ----
  k_zero<<<NBLK, 256, 0, stream>>>(deg);
  k_hist<<<(NE + 255) / 256, 256, 0, stream>>>(dstv, deg);
  k_blksum<<<NBLK, 256, 0, stream>>>(deg, blksum);
  k_blkscan<<<1, 256, 0, stream>>>(blksum, blkoff);
  k_scan3<<<NBLK, 256, 0, stream>>>(deg, blkoff, row_start, cursor, dinv, rdinv);
  k_scatter<<<(NE + 255) / 256, 256, 0, stream>>>(srcv, dstv, cursor, esrc);

  // ---- weight composition ----
  k_prep_misc<<<41, 256, 0, stream>>>(w2, fw2, w3, fw3, b1, fw1, fb1, b2, fb2, b3, fb3,
                                      Wc2, Wc3, bc1, bc2, bc3);
  k_prep_G<<<64, 256, 0, stream>>>(wd3, wf, G);
  k_prep_HA1<<<80, 256, 0, stream>>>(wd2, G, ws2, Hm, A1);
  k_prep_A32c0<<<97, 256, 0, stream>>>(wd1, ws1, Hm, G, wf, bd1, bs1, bd2, bs2, bd3, bf,
                                       A3, A2, c0);
  k_prep_pack<<<18, 256, 0, stream>>>(Wc3, A3 /*Acat*/, W3pk, Apk);

  // ---- pipeline ----
  k_gemm1t<<<(NN + 127) / 128, 256, 0, stream>>>(x, w1, dinv, h1);
  k_fuse1<<<NN / 8, 256, 0, stream>>>(h1, esrc, row_start, dinv, fw1, bc1, x1);
  k_fuse2<<<NN / 8, 256, 0, stream>>>(x1, esrc, row_start, dinv, Wc2, bc2, x2);
  k_gath64<<<NN / 4, 256, 0, stream>>>(x2, esrc, row_start, dinv, z3h);
  k_decode<<<(NN + 63) / 64, 256, 0, stream>>>(z3h, x2, x1, rdinv, (const half8*)W3pk,
                                               (const half8*)Apk, bc3, c0, outp);
}

// Round 8
// 219.202 us; speedup vs baseline: 1.0872x; 1.0872x over previous
//
#include <hip/hip_runtime.h>

#define NN 50000
#define NE 800000
#define NBLK 196  // ceil(NN/256); also = bucket count (256 nodes/bucket)

typedef _Float16 half8 __attribute__((ext_vector_type(8)));
typedef _Float16 half4 __attribute__((ext_vector_type(4)));
typedef float f32x4v __attribute__((ext_vector_type(4)));

// ---------------- CSR build ----------------
__global__ void k_zero(int* __restrict__ deg) {
  int i = blockIdx.x * 256 + threadIdx.x;
  if (i < NN) deg[i] = 0;
}

__global__ void k_hist(const int* __restrict__ dst, int* __restrict__ deg) {
  int e = blockIdx.x * 256 + threadIdx.x;
  if (e < NE) atomicAdd(&deg[dst[e]], 1);
}

__global__ void k_blksum(const int* __restrict__ deg, int* __restrict__ blksum) {
  __shared__ int s[256];
  int n = blockIdx.x * 256 + threadIdx.x;
  s[threadIdx.x] = (n < NN) ? deg[n] : 0;
  __syncthreads();
  for (int off = 128; off > 0; off >>= 1) {
    if (threadIdx.x < off) s[threadIdx.x] += s[threadIdx.x + off];
    __syncthreads();
  }
  if (threadIdx.x == 0) blksum[blockIdx.x] = s[0];
}

__global__ void k_blkscan(const int* __restrict__ blksum, int* __restrict__ blkoff) {
  __shared__ int s[256];
  int t = threadIdx.x;
  int v0 = (t < NBLK) ? blksum[t] : 0;
  s[t] = v0;
  __syncthreads();
  for (int off = 1; off < 256; off <<= 1) {
    int v = (t >= off) ? s[t - off] : 0;
    __syncthreads();
    s[t] += v;
    __syncthreads();
  }
  if (t < NBLK) blkoff[t] = s[t] - v0;  // exclusive
}

__global__ void k_scan3(const int* __restrict__ deg, const int* __restrict__ blkoff,
                        int* __restrict__ row_start,
                        float* __restrict__ dinv, float* __restrict__ rdinv) {
  __shared__ int s[256];
  int n = blockIdx.x * 256 + threadIdx.x;
  int d = (n < NN) ? deg[n] : 0;
  s[threadIdx.x] = d;
  __syncthreads();
  for (int off = 1; off < 256; off <<= 1) {
    int v = (threadIdx.x >= off) ? s[threadIdx.x - off] : 0;
    __syncthreads();
    s[threadIdx.x] += v;
    __syncthreads();
  }
  if (n < NN) {
    int rs = blkoff[blockIdx.x] + s[threadIdx.x] - d;
    row_start[n] = rs;
    float df = (float)d + 2.0f;
    dinv[n] = rsqrtf(df);
    rdinv[n] = sqrtf(df);
  }
  if (n == 0) row_start[NN] = NE;
}

__global__ void k_bcur(const int* __restrict__ row_start, int* __restrict__ bcur) {
  int t = threadIdx.x;
  bcur[t] = (t < NBLK) ? row_start[t * 256] : NE;
}

// ---- Pass 1: block-aggregated partition by dst>>8 into CSR bucket ranges ----
// Writes (src, dst&255) in ~16-edge contiguous runs per (block,bucket).
__launch_bounds__(256)
__global__ void k_part1(const int* __restrict__ srcv, const int* __restrict__ dstv,
                        int* __restrict__ bcur, int2* __restrict__ epk2) {
  __shared__ int cnt[256];
  __shared__ int base[256];
  int t = threadIdx.x;
  int e0 = blockIdx.x * 4096;
  cnt[t] = 0;
  __syncthreads();
  int src[16], dl[16], lo[16], bk[16];
  int m = 0;
#pragma unroll
  for (int i = 0; i < 16; ++i) {
    int e = e0 + i * 256 + t;
    if (e < NE) {
      int s = srcv[e], d = dstv[e];
      src[m] = s; bk[m] = d >> 8; dl[m] = d & 255;
      lo[m] = atomicAdd(&cnt[bk[m]], 1);
      ++m;
    }
  }
  __syncthreads();
  int c = cnt[t];
  if (c > 0) base[t] = atomicAdd(&bcur[t], c);
  __syncthreads();
  for (int i = 0; i < m; ++i) {
    int pos = base[bk[i]] + lo[i];
    epk2[pos] = make_int2(src[i], dl[i]);
  }
}

// ---- Pass 2: one block per bucket; exact per-node placement via LDS cursors ----
// All writes land in this bucket's contiguous CSR range (single-XCD L2-resident).
__launch_bounds__(256)
__global__ void k_part2(const int2* __restrict__ epk2, const int* __restrict__ row_start,
                        int* __restrict__ esrc) {
  __shared__ int cur[256];
  int t = threadIdx.x;
  int nbase = blockIdx.x * 256;
  int node = nbase + t;
  cur[t] = (node < NN) ? row_start[node] : NE;
  int rs0 = row_start[nbase];
  int nend = nbase + 256; if (nend > NN) nend = NN;
  int rs1 = row_start[nend];
  __syncthreads();
  for (int i = rs0 + t; i < rs1; i += 256) {
    int2 p = epk2[i];
    int tgt = atomicAdd(&cur[p.y], 1);
    esrc[tgt] = p.x;
  }
}

// ---------------- weight composition (tiny) ----------------
__global__ void k_prep_misc(const float* __restrict__ w2, const float* __restrict__ fw2,
                            const float* __restrict__ w3, const float* __restrict__ fw3,
                            const float* __restrict__ b1, const float* __restrict__ fw1,
                            const float* __restrict__ fb1,
                            const float* __restrict__ b2, const float* __restrict__ fb2,
                            const float* __restrict__ b3, const float* __restrict__ fb3,
                            float* __restrict__ Wc2, float* __restrict__ Wc3,
                            float* __restrict__ bc1, float* __restrict__ bc2,
                            float* __restrict__ bc3) {
  int id = blockIdx.x * 256 + threadIdx.x;
  if (id < 2048) {                       // Wc2 [32,64]
    int c = id >> 6, k = id & 63;
    float s = 0.f;
    for (int j = 0; j < 64; ++j) s = fmaf(w2[c * 64 + j], fw2[j * 64 + k], s);
    Wc2[id] = s;
  } else if (id < 10240) {               // Wc3 [64,128]
    int idx = id - 2048;
    int c = idx >> 7, k = idx & 127;
    float s = 0.f;
    for (int j = 0; j < 128; ++j) s = fmaf(w3[c * 128 + j], fw3[j * 128 + k], s);
    Wc3[idx] = s;
  } else if (id < 10272) {               // bc1 [32]
    int k = id - 10240;
    float s = fb1[k];
    for (int j = 0; j < 32; ++j) s = fmaf(b1[j], fw1[j * 32 + k], s);
    bc1[k] = s;
  } else if (id < 10336) {               // bc2 [64]
    int k = id - 10272;
    float s = fb2[k];
    for (int j = 0; j < 64; ++j) s = fmaf(b2[j], fw2[j * 64 + k], s);
    bc2[k] = s;
  } else if (id < 10464) {               // bc3 [128]
    int k = id - 10336;
    float s = fb3[k];
    for (int j = 0; j < 128; ++j) s = fmaf(b3[j], fw3[j * 128 + k], s);
    bc3[k] = s;
  }
}

__global__ void k_prep_G(const float* __restrict__ wd3, const float* __restrict__ wf,
                         float* __restrict__ G) {
  int id = blockIdx.x * 256 + threadIdx.x;
  if (id >= 16384) return;
  int k = id & 127, r = id >> 7;
  int c = r >> 2, l = r & 3;
  float s = 0.f;
  for (int o = 0; o < 32; ++o) {
    s = fmaf(wd3[c * 64 + o * 2 + 0], wf[(o * 8 + 2 * l + 0) * 128 + k], s);
    s = fmaf(wd3[c * 64 + o * 2 + 1], wf[(o * 8 + 2 * l + 1) * 128 + k], s);
  }
  G[r * 128 + k] = s;
}

__global__ void k_prep_HA1(const float* __restrict__ wd2, const float* __restrict__ G,
                           const float* __restrict__ ws2,
                           float* __restrict__ Hm, float* __restrict__ A1) {
  int id = blockIdx.x * 256 + threadIdx.x;
  if (id < 16384) {
    int k = id & 127, r = id >> 7;
    int c = r >> 1, l = r & 1;
    float s = 0.f;
    for (int o = 0; o < 32; ++o) {
      s = fmaf(wd2[c * 64 + o * 2 + 0], G[(o * 4 + 2 * l + 0) * 128 + k], s);
      s = fmaf(wd2[c * 64 + o * 2 + 1], G[(o * 4 + 2 * l + 1) * 128 + k], s);
    }
    Hm[r * 128 + k] = s;
  } else if (id < 16384 + 4096) {
    int idx = id - 16384;
    int k = idx & 127, c = idx >> 7;   // c < 32
    float s = 0.f;
    for (int o = 0; o < 32; ++o) {
      float g = G[(4 * o) * 128 + k] + G[(4 * o + 1) * 128 + k] +
                G[(4 * o + 2) * 128 + k] + G[(4 * o + 3) * 128 + k];
      s = fmaf(ws2[c * 32 + o], g, s);
    }
    A1[c * 128 + k] = s;
  }
}

__global__ void k_prep_A32c0(const float* __restrict__ wd1, const float* __restrict__ ws1,
                             const float* __restrict__ Hm, const float* __restrict__ G,
                             const float* __restrict__ wf,
                             const float* __restrict__ bd1, const float* __restrict__ bs1,
                             const float* __restrict__ bd2, const float* __restrict__ bs2,
                             const float* __restrict__ bd3, const float* __restrict__ bf,
                             float* __restrict__ A3, float* __restrict__ A2,
                             float* __restrict__ c0) {
  int id = blockIdx.x * 256 + threadIdx.x;
  if (id < 16384) {
    int k = id & 127, c = id >> 7;
    float s = 0.f;
    for (int j = 0; j < 128; ++j) s = fmaf(wd1[c * 128 + j], Hm[j * 128 + k], s);
    A3[c * 128 + k] = s;
  } else if (id < 16384 + 8192) {
    int idx = id - 16384;
    int k = idx & 127, c = idx >> 7;   // c < 64
    float s = 0.f;
    for (int o = 0; o < 64; ++o)
      s = fmaf(ws1[c * 64 + o], Hm[(2 * o) * 128 + k] + Hm[(2 * o + 1) * 128 + k], s);
    A2[c * 128 + k] = s;
  } else if (id < 16384 + 8192 + 128) {
    int k = id - 16384 - 8192;
    float s = bf[k];
    for (int o = 0; o < 64; ++o) {
      float b = bd1[o] + bs1[o];
      s = fmaf(b, Hm[(o * 2) * 128 + k] + Hm[(o * 2 + 1) * 128 + k], s);
    }
    for (int o = 0; o < 32; ++o) {
      float b = bd2[o] + bs2[o];
      float g = G[(o * 4) * 128 + k] + G[(o * 4 + 1) * 128 + k] +
                G[(o * 4 + 2) * 128 + k] + G[(o * 4 + 3) * 128 + k];
      s = fmaf(b, g, s);
    }
    for (int o = 0; o < 32; ++o) {
      float w8 = 0.f;
      for (int j = 0; j < 8; ++j) w8 += wf[(o * 8 + j) * 128 + k];
      s = fmaf(bd3[o], w8, s);
    }
    c0[k] = s;
  }
}

// -------- pack B fragments (f16) for mfma_f32_16x16x32_f16 --------
__global__ void k_prep_pack(const float* __restrict__ Wc3, const float* __restrict__ Acat,
                            _Float16* __restrict__ W3pk, _Float16* __restrict__ Apk) {
  int id = blockIdx.x * 256 + threadIdx.x;
  if (id < 1024) {
    int l = id & 63, nb = (id >> 6) & 7, kb = id >> 9;
    int kbase = kb * 32 + ((l >> 4) << 3);
    int col = nb * 16 + (l & 15);
#pragma unroll
    for (int j = 0; j < 8; ++j)
      W3pk[id * 8 + j] = (_Float16)Wc3[(kbase + j) * 128 + col];
  } else if (id < 1024 + 3584) {
    int idx = id - 1024;
    int l = idx & 63, nb = (idx >> 6) & 7, kb = idx >> 9;
    int kbase = kb * 32 + ((l >> 4) << 3);
    int col = nb * 16 + (l & 15);
#pragma unroll
    for (int j = 0; j < 8; ++j)
      Apk[idx * 8 + j] = (_Float16)Acat[(kbase + j) * 128 + col];
  }
}

// ---------------- layer-1: h1' = dinv[n] * (x @ w1), register-tiled ----------
__launch_bounds__(256)
__global__ void k_gemm1t(const float* __restrict__ X, const float* __restrict__ W,
                         const float* __restrict__ dinv, float* __restrict__ Y) {
  __shared__ float sW[128 * 32];
  __shared__ float sXc[128 * 33];
  int t = threadIdx.x;
  int n0 = blockIdx.x * 128;
#pragma unroll
  for (int it = 0; it < 4; ++it) {
    int idx = t + it * 256;
    int kr = idx >> 3, c4 = (idx & 7) * 4;
    *reinterpret_cast<float4*>(&sW[kr * 32 + c4]) =
        *reinterpret_cast<const float4*>(&W[kr * 32 + c4]);
  }
  int rg = t >> 3;
  int cg = t & 7;
  float acc[4][4];
#pragma unroll
  for (int r = 0; r < 4; ++r)
#pragma unroll
    for (int c = 0; c < 4; ++c) acc[r][c] = 0.f;

  for (int ch = 0; ch < 4; ++ch) {
    __syncthreads();
#pragma unroll
    for (int it = 0; it < 4; ++it) {
      int idx = t + it * 256;
      int row = idx & 127, k4 = (idx >> 7) * 4;
      int n = n0 + row;
      float4 v = make_float4(0.f, 0.f, 0.f, 0.f);
      if (n < NN) v = *reinterpret_cast<const float4*>(&X[(size_t)n * 128 + ch * 32 + k4]);
      sXc[row * 33 + k4 + 0] = v.x;
      sXc[row * 33 + k4 + 1] = v.y;
      sXc[row * 33 + k4 + 2] = v.z;
      sXc[row * 33 + k4 + 3] = v.w;
    }
    __syncthreads();
#pragma unroll
    for (int k = 0; k < 32; ++k) {
      float4 w = *reinterpret_cast<const float4*>(&sW[(ch * 32 + k) * 32 + cg * 4]);
#pragma unroll
      for (int r = 0; r < 4; ++r) {
        float xv = sXc[(rg * 4 + r) * 33 + k];
        acc[r][0] = fmaf(xv, w.x, acc[r][0]);
        acc[r][1] = fmaf(xv, w.y, acc[r][1]);
        acc[r][2] = fmaf(xv, w.z, acc[r][2]);
        acc[r][3] = fmaf(xv, w.w, acc[r][3]);
      }
    }
  }
#pragma unroll
  for (int r = 0; r < 4; ++r) {
    int n = n0 + rg * 4 + r;
    if (n < NN) {
      float dv = dinv[n];
      *reinterpret_cast<float4*>(&Y[(size_t)n * 32 + cg * 4]) =
          make_float4(dv * acc[r][0], dv * acc[r][1], dv * acc[r][2], dv * acc[r][3]);
    }
  }
}

// ---- coef-free 4-way gather sum for F=32 (input pre-scaled by dinv) ----
__device__ inline float4 gsum32(const float4* __restrict__ H4,
                                const int* __restrict__ esrc,
                                const int* __restrict__ row_start,
                                int n, int fg, int way) {
  float4 acc = make_float4(0.f, 0.f, 0.f, 0.f);
  if (way == 0) {
    float4 h = H4[(size_t)n * 8 + fg];
    acc.x = 2.f * h.x; acc.y = 2.f * h.y; acc.z = 2.f * h.z; acc.w = 2.f * h.w;
  }
  int end = row_start[n + 1];
  int i = row_start[n] + way;
  for (; i + 4 < end; i += 8) {
    int s0 = esrc[i], s1 = esrc[i + 4];
    float4 a = H4[(size_t)s0 * 8 + fg];
    float4 b = H4[(size_t)s1 * 8 + fg];
    acc.x += a.x; acc.y += a.y; acc.z += a.z; acc.w += a.w;
    acc.x += b.x; acc.y += b.y; acc.z += b.z; acc.w += b.w;
  }
  if (i < end) {
    int s = esrc[i];
    float4 a = H4[(size_t)s * 8 + fg];
    acc.x += a.x; acc.y += a.y; acc.z += a.z; acc.w += a.w;
  }
  acc.x += __shfl_xor(acc.x, 8);  acc.y += __shfl_xor(acc.y, 8);
  acc.z += __shfl_xor(acc.z, 8);  acc.w += __shfl_xor(acc.w, 8);
  acc.x += __shfl_xor(acc.x, 16); acc.y += __shfl_xor(acc.y, 16);
  acc.z += __shfl_xor(acc.z, 16); acc.w += __shfl_xor(acc.w, 16);
  return acc;
}

// ---- fused gather(F=32) + GEMM 32->32 + relu; in/out pre-scaled by dinv ----
__launch_bounds__(256)
__global__ void k_fuse1(const float* __restrict__ H, const int* __restrict__ esrc,
                        const int* __restrict__ row_start, const float* __restrict__ dinv,
                        const float* __restrict__ W, const float* __restrict__ bias,
                        float* __restrict__ Y) {
  __shared__ float sZT[32][9];   // [feat][node], z = dinv*S
  __shared__ float sW[32 * 32];
  int t = threadIdx.x;
  int n0 = blockIdx.x * 8;
  {
    int kr = t >> 3, c4 = (t & 7) * 4;
    *reinterpret_cast<float4*>(&sW[kr * 32 + c4]) =
        *reinterpret_cast<const float4*>(&W[kr * 32 + c4]);
  }
  int node = t >> 5, fg = t & 7, way = (t >> 3) & 3;
  int n = n0 + node;
  float4 z = gsum32(reinterpret_cast<const float4*>(H), esrc, row_start, n, fg, way);
  if (way == 0) {
    float dv = dinv[n];
    sZT[fg * 4 + 0][node] = dv * z.x;
    sZT[fg * 4 + 1][node] = dv * z.y;
    sZT[fg * 4 + 2][node] = dv * z.z;
    sZT[fg * 4 + 3][node] = dv * z.w;
  }
  __syncthreads();
  int nd = t >> 5, col = t & 31;
  float a = bias[col];
#pragma unroll
  for (int k = 0; k < 32; ++k) a = fmaf(sZT[k][nd], sW[k * 32 + col], a);
  Y[(size_t)(n0 + nd) * 32 + col] = dinv[n0 + nd] * fmaxf(a, 0.f);
}

// ---- fused gather(F=32) + GEMM 32->64 + relu; in/out pre-scaled by dinv ----
__launch_bounds__(256)
__global__ void k_fuse2(const float* __restrict__ H, const int* __restrict__ esrc,
                        const int* __restrict__ row_start, const float* __restrict__ dinv,
                        const float* __restrict__ W, const float* __restrict__ bias,
                        float* __restrict__ Y) {
  __shared__ float sZT[32][9];
  __shared__ float sW[32 * 64];
  int t = threadIdx.x;
  int n0 = blockIdx.x * 8;
#pragma unroll
  for (int it = 0; it < 2; ++it) {
    int idx = t + it * 256;
    int kr = idx >> 4, c4 = (idx & 15) * 4;
    *reinterpret_cast<float4*>(&sW[kr * 64 + c4]) =
        *reinterpret_cast<const float4*>(&W[kr * 64 + c4]);
  }
  int node = t >> 5, fg = t & 7, way = (t >> 3) & 3;
  int n = n0 + node;
  float4 z = gsum32(reinterpret_cast<const float4*>(H), esrc, row_start, n, fg, way);
  if (way == 0) {
    float dv = dinv[n];
    sZT[fg * 4 + 0][node] = dv * z.x;
    sZT[fg * 4 + 1][node] = dv * z.y;
    sZT[fg * 4 + 2][node] = dv * z.z;
    sZT[fg * 4 + 3][node] = dv * z.w;
  }
  __syncthreads();
  int nd = t >> 5, col = t & 31;
  float a = bias[col], b = bias[col + 32];
#pragma unroll
  for (int k = 0; k < 32; ++k) {
    float zv = sZT[k][nd];
    a = fmaf(zv, sW[k * 64 + col], a);
    b = fmaf(zv, sW[k * 64 + col + 32], b);
  }
  float dv = dinv[n0 + nd];
  Y[(size_t)(n0 + nd) * 64 + col] = dv * fmaxf(a, 0.f);
  Y[(size_t)(n0 + nd) * 64 + col + 32] = dv * fmaxf(b, 0.f);
}

// ------- coef-free 4-way gather F=64 -> z3 (true scale) as f16 -------
__launch_bounds__(256)
__global__ void k_gath64(const float* __restrict__ H, const int* __restrict__ esrc,
                         const int* __restrict__ row_start, const float* __restrict__ dinv,
                         _Float16* __restrict__ Zh) {
  int t = threadIdx.x;
  int n = blockIdx.x * 4 + (t >> 6);
  int fg = t & 15, way = (t >> 4) & 3;
  const float4* H4 = reinterpret_cast<const float4*>(H);
  float4 acc = make_float4(0.f, 0.f, 0.f, 0.f);
  if (way == 0) {
    float4 h = H4[(size_t)n * 16 + fg];
    acc.x = 2.f * h.x; acc.y = 2.f * h.y; acc.z = 2.f * h.z; acc.w = 2.f * h.w;
  }
  int end = row_start[n + 1];
  int i = row_start[n] + way;
  for (; i + 4 < end; i += 8) {
    int s0 = esrc[i], s1 = esrc[i + 4];
    float4 a = H4[(size_t)s0 * 16 + fg];
    float4 b = H4[(size_t)s1 * 16 + fg];
    acc.x += a.x; acc.y += a.y; acc.z += a.z; acc.w += a.w;
    acc.x += b.x; acc.y += b.y; acc.z += b.z; acc.w += b.w;
  }
  if (i < end) {
    int s = esrc[i];
    float4 a = H4[(size_t)s * 16 + fg];
    acc.x += a.x; acc.y += a.y; acc.z += a.z; acc.w += a.w;
  }
  acc.x += __shfl_xor(acc.x, 16); acc.y += __shfl_xor(acc.y, 16);
  acc.z += __shfl_xor(acc.z, 16); acc.w += __shfl_xor(acc.w, 16);
  acc.x += __shfl_xor(acc.x, 32); acc.y += __shfl_xor(acc.y, 32);
  acc.z += __shfl_xor(acc.z, 32); acc.w += __shfl_xor(acc.w, 32);
  if (way == 0) {
    float dv = dinv[n];
    half4 hv;
    hv[0] = (_Float16)(dv * acc.x); hv[1] = (_Float16)(dv * acc.y);
    hv[2] = (_Float16)(dv * acc.z); hv[3] = (_Float16)(dv * acc.w);
    *reinterpret_cast<half4*>(Zh + (size_t)n * 64 + fg * 4) = hv;
  }
}

// ---- convert 8 f32 -> half8 fragment, with scale ----
__device__ inline half8 cvt8s(const float* __restrict__ p, float s) {
  float4 u = *reinterpret_cast<const float4*>(p);
  float4 v = *reinterpret_cast<const float4*>(p + 4);
  half8 a;
  a[0] = (_Float16)(s * u.x); a[1] = (_Float16)(s * u.y);
  a[2] = (_Float16)(s * u.z); a[3] = (_Float16)(s * u.w);
  a[4] = (_Float16)(s * v.x); a[5] = (_Float16)(s * v.y);
  a[6] = (_Float16)(s * v.z); a[7] = (_Float16)(s * v.w);
  return a;
}

// ------- MFMA decode: x3 = relu(z3@Wc3+bc3); out = c0 + [x3|x2|x1] @ Acat -------
__launch_bounds__(256)
__global__ void k_decode(const _Float16* __restrict__ z3h, const float* __restrict__ X2,
                         const float* __restrict__ X1, const float* __restrict__ rdinv,
                         const half8* __restrict__ W3pk, const half8* __restrict__ Apk,
                         const float* __restrict__ bc3, const float* __restrict__ c0,
                         float* __restrict__ out) {
  __shared__ _Float16 sX3[4][16][136];
  int t = threadIdx.x;
  int w = t >> 6, l = t & 63;
  int m16 = l & 15, g = l >> 4;
  int n0 = blockIdx.x * 64 + w * 16;
  int nrow = n0 + m16;

  f32x4v acc[8];
  // ---- Phase B: x3 = relu(z3 @ Wc3 + bc3), K=64 ----
#pragma unroll
  for (int nb = 0; nb < 8; ++nb) {
    float bv = bc3[nb * 16 + m16];
    acc[nb] = (f32x4v){bv, bv, bv, bv};
  }
#pragma unroll
  for (int kb = 0; kb < 2; ++kb) {
    half8 a = *reinterpret_cast<const half8*>(z3h + (size_t)nrow * 64 + kb * 32 + g * 8);
#pragma unroll
    for (int nb = 0; nb < 8; ++nb) {
      half8 b = W3pk[(kb * 8 + nb) * 64 + l];
      acc[nb] = __builtin_amdgcn_mfma_f32_16x16x32_f16(a, b, acc[nb], 0, 0, 0);
    }
  }
#pragma unroll
  for (int nb = 0; nb < 8; ++nb)
#pragma unroll
    for (int r = 0; r < 4; ++r)
      sX3[w][g * 4 + r][nb * 16 + m16] = (_Float16)fmaxf(acc[nb][r], 0.0f);
  __syncthreads();

  // ---- Phase C: out = c0 + [x3|x2|x1] @ Acat, K=224 ----
  float rd = rdinv[nrow];
#pragma unroll
  for (int nb = 0; nb < 8; ++nb) {
    float cv = c0[nb * 16 + m16];
    acc[nb] = (f32x4v){cv, cv, cv, cv};
  }
#pragma unroll
  for (int kb = 0; kb < 7; ++kb) {
    half8 a;
    if (kb < 4)
      a = *reinterpret_cast<const half8*>(&sX3[w][m16][kb * 32 + g * 8]);
    else if (kb < 6)
      a = cvt8s(X2 + (size_t)nrow * 64 + (kb - 4) * 32 + g * 8, rd);
    else
      a = cvt8s(X1 + (size_t)nrow * 32 + g * 8, rd);
#pragma unroll
    for (int nb = 0; nb < 8; ++nb) {
      half8 b = Apk[(kb * 8 + nb) * 64 + l];
      acc[nb] = __builtin_amdgcn_mfma_f32_16x16x32_f16(a, b, acc[nb], 0, 0, 0);
    }
  }
#pragma unroll
  for (int nb = 0; nb < 8; ++nb)
#pragma unroll
    for (int r = 0; r < 4; ++r) {
      int n = n0 + g * 4 + r;
      if (n < NN) out[(size_t)n * 128 + nb * 16 + m16] = acc[nb][r];
    }
}

extern "C" void kernel_launch(void* const* d_in, const int* in_sizes, int n_in,
                              void* d_out, int out_size, void* d_ws, size_t ws_size,
                              hipStream_t stream) {
  const float* x   = (const float*)d_in[0];
  const int* ei    = (const int*)d_in[1];
  const int* srcv  = ei;
  const int* dstv  = ei + NE;
  const float* w1  = (const float*)d_in[2];
  const float* b1  = (const float*)d_in[3];
  const float* fw1 = (const float*)d_in[4];
  const float* fb1 = (const float*)d_in[5];
  const float* w2  = (const float*)d_in[6];
  const float* b2  = (const float*)d_in[7];
  const float* fw2 = (const float*)d_in[8];
  const float* fb2 = (const float*)d_in[9];
  const float* w3  = (const float*)d_in[10];
  const float* b3  = (const float*)d_in[11];
  const float* fw3 = (const float*)d_in[12];
  const float* fb3 = (const float*)d_in[13];
  const float* wd1 = (const float*)d_in[14];
  const float* bd1 = (const float*)d_in[15];
  const float* wd2 = (const float*)d_in[16];
  const float* bd2 = (const float*)d_in[17];
  const float* wd3 = (const float*)d_in[18];
  const float* bd3 = (const float*)d_in[19];
  const float* ws1 = (const float*)d_in[20];
  const float* bs1 = (const float*)d_in[21];
  const float* ws2 = (const float*)d_in[22];
  const float* bs2 = (const float*)d_in[23];
  const float* wf  = (const float*)d_in[24];
  const float* bf  = (const float*)d_in[25];

  float* fp = (float*)d_ws;
  float* dinv = fp;                  // 50176
  float* rdinv= dinv + 50176;        // 50176
  float* h1   = rdinv + 50176;       // 50048*32 f32; later overlaid by z3h (f16)
  float* x1   = h1 + 1601536;        // 50048*32 (pre-scaled by dinv)
  float* x2   = x1 + 1601536;        // 50048*64 (pre-scaled by dinv)
  float* Wc2  = x2 + 3203072;        // 2048
  float* Wc3  = Wc2 + 2048;          // 8192
  float* bc1  = Wc3 + 8192;          // 64
  float* bc2  = bc1 + 64;            // 64
  float* bc3  = bc2 + 64;            // 128
  float* G    = bc3 + 128;           // 16384
  float* Hm   = G + 16384;           // 16384
  float* A3   = Hm + 16384;          // 16384 } Acat = A3|A2|A1 contiguous [224][128]
  float* A2   = A3 + 16384;          // 8192  }
  float* A1   = A2 + 8192;           // 4096  }
  float* c0   = A1 + 4096;           // 256
  _Float16* W3pk = (_Float16*)(c0 + 256);   // 8192 halves
  _Float16* Apk  = W3pk + 8192;             // 28672 halves
  int* ip     = (int*)(Apk + 28672);
  int* esrc   = ip;                  // 800000 int (final CSR src list)
  int2* epk2  = (int2*)(esrc + 800000); // 800000 int2 (bucket-partitioned temp)
  int* deg    = (int*)(epk2 + 800000);  // 50176
  int* row_start = deg + 50176;      // 50176 (NN+1 used)
  int* blksum = row_start + 50176;   // 256
  int* blkoff = blksum + 256;        // 256
  int* bcur   = blkoff + 256;        // 256

  _Float16* z3h = (_Float16*)h1;     // overlay: h1 dead after k_fuse1
  float* outp = (float*)d_out;

  // ---- CSR build (two-pass coalesced partition) ----
  k_zero<<<NBLK, 256, 0, stream>>>(deg);
  k_hist<<<(NE + 255) / 256, 256, 0, stream>>>(dstv, deg);
  k_blksum<<<NBLK, 256, 0, stream>>>(deg, blksum);
  k_blkscan<<<1, 256, 0, stream>>>(blksum, blkoff);
  k_scan3<<<NBLK, 256, 0, stream>>>(deg, blkoff, row_start, dinv, rdinv);
  k_bcur<<<1, 256, 0, stream>>>(row_start, bcur);
  k_part1<<<(NE + 4095) / 4096, 256, 0, stream>>>(srcv, dstv, bcur, epk2);
  k_part2<<<NBLK, 256, 0, stream>>>(epk2, row_start, esrc);

  // ---- weight composition ----
  k_prep_misc<<<41, 256, 0, stream>>>(w2, fw2, w3, fw3, b1, fw1, fb1, b2, fb2, b3, fb3,
                                      Wc2, Wc3, bc1, bc2, bc3);
  k_prep_G<<<64, 256, 0, stream>>>(wd3, wf, G);
  k_prep_HA1<<<80, 256, 0, stream>>>(wd2, G, ws2, Hm, A1);
  k_prep_A32c0<<<97, 256, 0, stream>>>(wd1, ws1, Hm, G, wf, bd1, bs1, bd2, bs2, bd3, bf,
                                       A3, A2, c0);
  k_prep_pack<<<18, 256, 0, stream>>>(Wc3, A3 /*Acat*/, W3pk, Apk);

  // ---- pipeline ----
  k_gemm1t<<<(NN + 127) / 128, 256, 0, stream>>>(x, w1, dinv, h1);
  k_fuse1<<<NN / 8, 256, 0, stream>>>(h1, esrc, row_start, dinv, fw1, bc1, x1);
  k_fuse2<<<NN / 8, 256, 0, stream>>>(x1, esrc, row_start, dinv, Wc2, bc2, x2);
  k_gath64<<<NN / 4, 256, 0, stream>>>(x2, esrc, row_start, dinv, z3h);
  k_decode<<<(NN + 63) / 64, 256, 0, stream>>>(z3h, x2, x1, rdinv, (const half8*)W3pk,
                                               (const half8*)Apk, bc3, c0, outp);
}

// Round 9
// 204.391 us; speedup vs baseline: 1.1659x; 1.0725x over previous
//
#include <hip/hip_runtime.h>

#define NN 50000
#define NE 800000
#define NBLK 196  // ceil(NN/256); also bucket count (256 nodes/bucket)

typedef _Float16 half8 __attribute__((ext_vector_type(8)));
typedef _Float16 half4 __attribute__((ext_vector_type(4)));
typedef float f32x4v __attribute__((ext_vector_type(4)));

// ---------------- CSR build ----------------
__global__ void k_zero(int* __restrict__ deg) {
  int i = blockIdx.x * 256 + threadIdx.x;
  if (i < NN) deg[i] = 0;
}

__global__ void k_hist(const int* __restrict__ dst, int* __restrict__ deg) {
  int e = blockIdx.x * 256 + threadIdx.x;
  if (e < NE) atomicAdd(&deg[dst[e]], 1);
}

__global__ void k_blksum(const int* __restrict__ deg, int* __restrict__ blksum) {
  __shared__ int s[256];
  int n = blockIdx.x * 256 + threadIdx.x;
  s[threadIdx.x] = (n < NN) ? deg[n] : 0;
  __syncthreads();
  for (int off = 128; off > 0; off >>= 1) {
    if (threadIdx.x < off) s[threadIdx.x] += s[threadIdx.x + off];
    __syncthreads();
  }
  if (threadIdx.x == 0) blksum[blockIdx.x] = s[0];
}

// exclusive scan of block sums; bcur[b] = blkoff[b] (= row_start[b*256])
__global__ void k_blkscan(const int* __restrict__ blksum, int* __restrict__ blkoff,
                          int* __restrict__ bcur) {
  __shared__ int s[256];
  int t = threadIdx.x;
  int v0 = (t < NBLK) ? blksum[t] : 0;
  s[t] = v0;
  __syncthreads();
  for (int off = 1; off < 256; off <<= 1) {
    int v = (t >= off) ? s[t - off] : 0;
    __syncthreads();
    s[t] += v;
    __syncthreads();
  }
  int e = s[t] - v0;
  if (t < NBLK) { blkoff[t] = e; bcur[t] = e; }
}

__global__ void k_scan3(const int* __restrict__ deg, const int* __restrict__ blkoff,
                        int* __restrict__ row_start,
                        float* __restrict__ dinv, float* __restrict__ rdinv) {
  __shared__ int s[256];
  int n = blockIdx.x * 256 + threadIdx.x;
  int d = (n < NN) ? deg[n] : 0;
  s[threadIdx.x] = d;
  __syncthreads();
  for (int off = 1; off < 256; off <<= 1) {
    int v = (threadIdx.x >= off) ? s[threadIdx.x - off] : 0;
    __syncthreads();
    s[threadIdx.x] += v;
    __syncthreads();
  }
  if (n < NN) {
    int rs = blkoff[blockIdx.x] + s[threadIdx.x] - d;
    row_start[n] = rs;
    float df = (float)d + 2.0f;
    dinv[n] = rsqrtf(df);
    rdinv[n] = sqrtf(df);
  }
  if (n == 0) row_start[NN] = NE;
}

// ---- Pass 1: block-aggregated partition by dst>>8 into CSR bucket ranges ----
__launch_bounds__(256)
__global__ void k_part1(const int* __restrict__ srcv, const int* __restrict__ dstv,
                        int* __restrict__ bcur, int2* __restrict__ epk2) {
  __shared__ int cnt[256];
  __shared__ int base[256];
  int t = threadIdx.x;
  int e0 = blockIdx.x * 4096;
  cnt[t] = 0;
  __syncthreads();
  int src[16], dl[16], lo[16], bk[16];
  int m = 0;
#pragma unroll
  for (int i = 0; i < 16; ++i) {
    int e = e0 + i * 256 + t;
    if (e < NE) {
      int s = srcv[e], d = dstv[e];
      src[m] = s; bk[m] = d >> 8; dl[m] = d & 255;
      lo[m] = atomicAdd(&cnt[bk[m]], 1);
      ++m;
    }
  }
  __syncthreads();
  int c = cnt[t];
  if (c > 0) base[t] = atomicAdd(&bcur[t], c);
  __syncthreads();
  for (int i = 0; i < m; ++i) {
    int pos = base[bk[i]] + lo[i];
    epk2[pos] = make_int2(src[i], dl[i]);
  }
}

// ---- Pass 2: one block per bucket; exact per-node placement via LDS cursors ----
__launch_bounds__(256)
__global__ void k_part2(const int2* __restrict__ epk2, const int* __restrict__ row_start,
                        int* __restrict__ esrc) {
  __shared__ int cur[256];
  int t = threadIdx.x;
  int nbase = blockIdx.x * 256;
  int node = nbase + t;
  cur[t] = (node < NN) ? row_start[node] : NE;
  int rs0 = row_start[nbase];
  int nend = nbase + 256; if (nend > NN) nend = NN;
  int rs1 = row_start[nend];
  __syncthreads();
  for (int i = rs0 + t; i < rs1; i += 256) {
    int2 p = epk2[i];
    int tgt = atomicAdd(&cur[p.y], 1);
    esrc[tgt] = p.x;
  }
}

// ------- weight composition: G[128][128] + {Wc2, Wc3, bc1, bc2, bc3} merged -------
__global__ void k_prep1(const float* __restrict__ wd3, const float* __restrict__ wf,
                        const float* __restrict__ w2, const float* __restrict__ fw2,
                        const float* __restrict__ w3, const float* __restrict__ fw3,
                        const float* __restrict__ b1, const float* __restrict__ fw1,
                        const float* __restrict__ fb1,
                        const float* __restrict__ b2, const float* __restrict__ fb2,
                        const float* __restrict__ b3, const float* __restrict__ fb3,
                        float* __restrict__ G,
                        float* __restrict__ Wc2, float* __restrict__ Wc3,
                        float* __restrict__ bc1, float* __restrict__ bc2,
                        float* __restrict__ bc3) {
  int id = blockIdx.x * 256 + threadIdx.x;
  if (id < 16384) {                      // G[c*4+l, k]
    int k = id & 127, r = id >> 7;
    int c = r >> 2, l = r & 3;
    float s = 0.f;
    for (int o = 0; o < 32; ++o) {
      s = fmaf(wd3[c * 64 + o * 2 + 0], wf[(o * 8 + 2 * l + 0) * 128 + k], s);
      s = fmaf(wd3[c * 64 + o * 2 + 1], wf[(o * 8 + 2 * l + 1) * 128 + k], s);
    }
    G[r * 128 + k] = s;
    return;
  }
  int id2 = id - 16384;
  if (id2 < 2048) {                      // Wc2 [32,64]
    int c = id2 >> 6, k = id2 & 63;
    float s = 0.f;
    for (int j = 0; j < 64; ++j) s = fmaf(w2[c * 64 + j], fw2[j * 64 + k], s);
    Wc2[id2] = s;
  } else if (id2 < 10240) {              // Wc3 [64,128]
    int idx = id2 - 2048;
    int c = idx >> 7, k = idx & 127;
    float s = 0.f;
    for (int j = 0; j < 128; ++j) s = fmaf(w3[c * 128 + j], fw3[j * 128 + k], s);
    Wc3[idx] = s;
  } else if (id2 < 10272) {              // bc1 [32]
    int k = id2 - 10240;
    float s = fb1[k];
    for (int j = 0; j < 32; ++j) s = fmaf(b1[j], fw1[j * 32 + k], s);
    bc1[k] = s;
  } else if (id2 < 10336) {              // bc2 [64]
    int k = id2 - 10272;
    float s = fb2[k];
    for (int j = 0; j < 64; ++j) s = fmaf(b2[j], fw2[j * 64 + k], s);
    bc2[k] = s;
  } else if (id2 < 10464) {              // bc3 [128]
    int k = id2 - 10336;
    float s = fb3[k];
    for (int j = 0; j < 128; ++j) s = fmaf(b3[j], fw3[j * 128 + k], s);
    bc3[k] = s;
  }
}

__global__ void k_prep_HA1(const float* __restrict__ wd2, const float* __restrict__ G,
                           const float* __restrict__ ws2,
                           float* __restrict__ Hm, float* __restrict__ A1) {
  int id = blockIdx.x * 256 + threadIdx.x;
  if (id < 16384) {
    int k = id & 127, r = id >> 7;
    int c = r >> 1, l = r & 1;
    float s = 0.f;
    for (int o = 0; o < 32; ++o) {
      s = fmaf(wd2[c * 64 + o * 2 + 0], G[(o * 4 + 2 * l + 0) * 128 + k], s);
      s = fmaf(wd2[c * 64 + o * 2 + 1], G[(o * 4 + 2 * l + 1) * 128 + k], s);
    }
    Hm[r * 128 + k] = s;
  } else if (id < 16384 + 4096) {
    int idx = id - 16384;
    int k = idx & 127, c = idx >> 7;   // c < 32
    float s = 0.f;
    for (int o = 0; o < 32; ++o) {
      float g = G[(4 * o) * 128 + k] + G[(4 * o + 1) * 128 + k] +
                G[(4 * o + 2) * 128 + k] + G[(4 * o + 3) * 128 + k];
      s = fmaf(ws2[c * 32 + o], g, s);
    }
    A1[c * 128 + k] = s;
  }
}

__global__ void k_prep_A32c0(const float* __restrict__ wd1, const float* __restrict__ ws1,
                             const float* __restrict__ Hm, const float* __restrict__ G,
                             const float* __restrict__ wf,
                             const float* __restrict__ bd1, const float* __restrict__ bs1,
                             const float* __restrict__ bd2, const float* __restrict__ bs2,
                             const float* __restrict__ bd3, const float* __restrict__ bf,
                             float* __restrict__ A3, float* __restrict__ A2,
                             float* __restrict__ c0) {
  int id = blockIdx.x * 256 + threadIdx.x;
  if (id < 16384) {
    int k = id & 127, c = id >> 7;
    float s = 0.f;
    for (int j = 0; j < 128; ++j) s = fmaf(wd1[c * 128 + j], Hm[j * 128 + k], s);
    A3[c * 128 + k] = s;
  } else if (id < 16384 + 8192) {
    int idx = id - 16384;
    int k = idx & 127, c = idx >> 7;   // c < 64
    float s = 0.f;
    for (int o = 0; o < 64; ++o)
      s = fmaf(ws1[c * 64 + o], Hm[(2 * o) * 128 + k] + Hm[(2 * o + 1) * 128 + k], s);
    A2[c * 128 + k] = s;
  } else if (id < 16384 + 8192 + 128) {
    int k = id - 16384 - 8192;
    float s = bf[k];
    for (int o = 0; o < 64; ++o) {
      float b = bd1[o] + bs1[o];
      s = fmaf(b, Hm[(o * 2) * 128 + k] + Hm[(o * 2 + 1) * 128 + k], s);
    }
    for (int o = 0; o < 32; ++o) {
      float b = bd2[o] + bs2[o];
      float g = G[(o * 4) * 128 + k] + G[(o * 4 + 1) * 128 + k] +
                G[(o * 4 + 2) * 128 + k] + G[(o * 4 + 3) * 128 + k];
      s = fmaf(b, g, s);
    }
    for (int o = 0; o < 32; ++o) {
      float w8 = 0.f;
      for (int j = 0; j < 8; ++j) w8 += wf[(o * 8 + j) * 128 + k];
      s = fmaf(bd3[o], w8, s);
    }
    c0[k] = s;
  }
}

// -------- pack B fragments (f16) for mfma_f32_16x16x32_f16 --------
__global__ void k_prep_pack(const float* __restrict__ Wc3, const float* __restrict__ Acat,
                            _Float16* __restrict__ W3pk, _Float16* __restrict__ Apk) {
  int id = blockIdx.x * 256 + threadIdx.x;
  if (id < 1024) {
    int l = id & 63, nb = (id >> 6) & 7, kb = id >> 9;
    int kbase = kb * 32 + ((l >> 4) << 3);
    int col = nb * 16 + (l & 15);
#pragma unroll
    for (int j = 0; j < 8; ++j)
      W3pk[id * 8 + j] = (_Float16)Wc3[(kbase + j) * 128 + col];
  } else if (id < 1024 + 3584) {
    int idx = id - 1024;
    int l = idx & 63, nb = (idx >> 6) & 7, kb = idx >> 9;
    int kbase = kb * 32 + ((l >> 4) << 3);
    int col = nb * 16 + (l & 15);
#pragma unroll
    for (int j = 0; j < 8; ++j)
      Apk[idx * 8 + j] = (_Float16)Acat[(kbase + j) * 128 + col];
  }
}

// ---------------- layer-1: h1' = dinv[n] * (x @ w1), register-tiled ----------
__launch_bounds__(256)
__global__ void k_gemm1t(const float* __restrict__ X, const float* __restrict__ W,
                         const float* __restrict__ dinv, float* __restrict__ Y) {
  __shared__ float sW[128 * 32];
  __shared__ float sXc[128 * 33];
  int t = threadIdx.x;
  int n0 = blockIdx.x * 128;
#pragma unroll
  for (int it = 0; it < 4; ++it) {
    int idx = t + it * 256;
    int kr = idx >> 3, c4 = (idx & 7) * 4;
    *reinterpret_cast<float4*>(&sW[kr * 32 + c4]) =
        *reinterpret_cast<const float4*>(&W[kr * 32 + c4]);
  }
  int rg = t >> 3;
  int cg = t & 7;
  float acc[4][4];
#pragma unroll
  for (int r = 0; r < 4; ++r)
#pragma unroll
    for (int c = 0; c < 4; ++c) acc[r][c] = 0.f;

  for (int ch = 0; ch < 4; ++ch) {
    __syncthreads();
#pragma unroll
    for (int it = 0; it < 4; ++it) {
      int idx = t + it * 256;
      int row = idx & 127, k4 = (idx >> 7) * 4;
      int n = n0 + row;
      float4 v = make_float4(0.f, 0.f, 0.f, 0.f);
      if (n < NN) v = *reinterpret_cast<const float4*>(&X[(size_t)n * 128 + ch * 32 + k4]);
      sXc[row * 33 + k4 + 0] = v.x;
      sXc[row * 33 + k4 + 1] = v.y;
      sXc[row * 33 + k4 + 2] = v.z;
      sXc[row * 33 + k4 + 3] = v.w;
    }
    __syncthreads();
#pragma unroll
    for (int k = 0; k < 32; ++k) {
      float4 w = *reinterpret_cast<const float4*>(&sW[(ch * 32 + k) * 32 + cg * 4]);
#pragma unroll
      for (int r = 0; r < 4; ++r) {
        float xv = sXc[(rg * 4 + r) * 33 + k];
        acc[r][0] = fmaf(xv, w.x, acc[r][0]);
        acc[r][1] = fmaf(xv, w.y, acc[r][1]);
        acc[r][2] = fmaf(xv, w.z, acc[r][2]);
        acc[r][3] = fmaf(xv, w.w, acc[r][3]);
      }
    }
  }
#pragma unroll
  for (int r = 0; r < 4; ++r) {
    int n = n0 + rg * 4 + r;
    if (n < NN) {
      float dv = dinv[n];
      *reinterpret_cast<float4*>(&Y[(size_t)n * 32 + cg * 4]) =
          make_float4(dv * acc[r][0], dv * acc[r][1], dv * acc[r][2], dv * acc[r][3]);
    }
  }
}

// ---- coef-free 4-way gather sum, f32 rows F=32 (for fuse1: h1 is f32) ----
__device__ inline float4 gsum32(const float4* __restrict__ H4,
                                const int* __restrict__ esrc,
                                const int* __restrict__ row_start,
                                int n, int fg, int way) {
  float4 acc = make_float4(0.f, 0.f, 0.f, 0.f);
  if (way == 0) {
    float4 h = H4[(size_t)n * 8 + fg];
    acc.x = 2.f * h.x; acc.y = 2.f * h.y; acc.z = 2.f * h.z; acc.w = 2.f * h.w;
  }
  int end = row_start[n + 1];
  int i = row_start[n] + way;
  for (; i + 4 < end; i += 8) {
    int s0 = esrc[i], s1 = esrc[i + 4];
    float4 a = H4[(size_t)s0 * 8 + fg];
    float4 b = H4[(size_t)s1 * 8 + fg];
    acc.x += a.x; acc.y += a.y; acc.z += a.z; acc.w += a.w;
    acc.x += b.x; acc.y += b.y; acc.z += b.z; acc.w += b.w;
  }
  if (i < end) {
    int s = esrc[i];
    float4 a = H4[(size_t)s * 8 + fg];
    acc.x += a.x; acc.y += a.y; acc.z += a.z; acc.w += a.w;
  }
  acc.x += __shfl_xor(acc.x, 8);  acc.y += __shfl_xor(acc.y, 8);
  acc.z += __shfl_xor(acc.z, 8);  acc.w += __shfl_xor(acc.w, 8);
  acc.x += __shfl_xor(acc.x, 16); acc.y += __shfl_xor(acc.y, 16);
  acc.z += __shfl_xor(acc.z, 16); acc.w += __shfl_xor(acc.w, 16);
  return acc;
}

// ---- coef-free 4-way gather sum, f16 rows F=32 (for fuse2: x1 is f16) ----
__device__ inline float4 gsum32h(const half4* __restrict__ H4,
                                 const int* __restrict__ esrc,
                                 const int* __restrict__ row_start,
                                 int n, int fg, int way) {
  float4 acc = make_float4(0.f, 0.f, 0.f, 0.f);
  if (way == 0) {
    half4 h = H4[(size_t)n * 8 + fg];
    acc.x = 2.f * (float)h[0]; acc.y = 2.f * (float)h[1];
    acc.z = 2.f * (float)h[2]; acc.w = 2.f * (float)h[3];
  }
  int end = row_start[n + 1];
  int i = row_start[n] + way;
  for (; i + 4 < end; i += 8) {
    int s0 = esrc[i], s1 = esrc[i + 4];
    half4 a = H4[(size_t)s0 * 8 + fg];
    half4 b = H4[(size_t)s1 * 8 + fg];
    acc.x += (float)a[0] + (float)b[0];
    acc.y += (float)a[1] + (float)b[1];
    acc.z += (float)a[2] + (float)b[2];
    acc.w += (float)a[3] + (float)b[3];
  }
  if (i < end) {
    int s = esrc[i];
    half4 a = H4[(size_t)s * 8 + fg];
    acc.x += (float)a[0]; acc.y += (float)a[1];
    acc.z += (float)a[2]; acc.w += (float)a[3];
  }
  acc.x += __shfl_xor(acc.x, 8);  acc.y += __shfl_xor(acc.y, 8);
  acc.z += __shfl_xor(acc.z, 8);  acc.w += __shfl_xor(acc.w, 8);
  acc.x += __shfl_xor(acc.x, 16); acc.y += __shfl_xor(acc.y, 16);
  acc.z += __shfl_xor(acc.z, 16); acc.w += __shfl_xor(acc.w, 16);
  return acc;
}

// ---- fuse1: gather(h1 f32) + GEMM 32->32 + relu -> x1 (f16, pre-scaled) ----
__launch_bounds__(256)
__global__ void k_fuse1(const float* __restrict__ H, const int* __restrict__ esrc,
                        const int* __restrict__ row_start, const float* __restrict__ dinv,
                        const float* __restrict__ W, const float* __restrict__ bias,
                        _Float16* __restrict__ Y) {
  __shared__ float sZT[32][9];   // [feat][node], z = dinv*S
  __shared__ float sW[32 * 32];
  int t = threadIdx.x;
  int n0 = blockIdx.x * 8;
  {
    int kr = t >> 3, c4 = (t & 7) * 4;
    *reinterpret_cast<float4*>(&sW[kr * 32 + c4]) =
        *reinterpret_cast<const float4*>(&W[kr * 32 + c4]);
  }
  int node = t >> 5, fg = t & 7, way = (t >> 3) & 3;
  int n = n0 + node;
  float4 z = gsum32(reinterpret_cast<const float4*>(H), esrc, row_start, n, fg, way);
  if (way == 0) {
    float dv = dinv[n];
    sZT[fg * 4 + 0][node] = dv * z.x;
    sZT[fg * 4 + 1][node] = dv * z.y;
    sZT[fg * 4 + 2][node] = dv * z.z;
    sZT[fg * 4 + 3][node] = dv * z.w;
  }
  __syncthreads();
  int nd = t >> 5, col = t & 31;
  float a = bias[col];
#pragma unroll
  for (int k = 0; k < 32; ++k) a = fmaf(sZT[k][nd], sW[k * 32 + col], a);
  Y[(size_t)(n0 + nd) * 32 + col] = (_Float16)(dinv[n0 + nd] * fmaxf(a, 0.f));
}

// ---- fuse2: gather(x1 f16) + GEMM 32->64 + relu -> x2 (f16, pre-scaled) ----
__launch_bounds__(256)
__global__ void k_fuse2(const _Float16* __restrict__ H, const int* __restrict__ esrc,
                        const int* __restrict__ row_start, const float* __restrict__ dinv,
                        const float* __restrict__ W, const float* __restrict__ bias,
                        _Float16* __restrict__ Y) {
  __shared__ float sZT[32][9];
  __shared__ float sW[32 * 64];
  int t = threadIdx.x;
  int n0 = blockIdx.x * 8;
#pragma unroll
  for (int it = 0; it < 2; ++it) {
    int idx = t + it * 256;
    int kr = idx >> 4, c4 = (idx & 15) * 4;
    *reinterpret_cast<float4*>(&sW[kr * 64 + c4]) =
        *reinterpret_cast<const float4*>(&W[kr * 64 + c4]);
  }
  int node = t >> 5, fg = t & 7, way = (t >> 3) & 3;
  int n = n0 + node;
  float4 z = gsum32h(reinterpret_cast<const half4*>(H), esrc, row_start, n, fg, way);
  if (way == 0) {
    float dv = dinv[n];
    sZT[fg * 4 + 0][node] = dv * z.x;
    sZT[fg * 4 + 1][node] = dv * z.y;
    sZT[fg * 4 + 2][node] = dv * z.z;
    sZT[fg * 4 + 3][node] = dv * z.w;
  }
  __syncthreads();
  int nd = t >> 5, col = t & 31;
  float a = bias[col], b = bias[col + 32];
#pragma unroll
  for (int k = 0; k < 32; ++k) {
    float zv = sZT[k][nd];
    a = fmaf(zv, sW[k * 64 + col], a);
    b = fmaf(zv, sW[k * 64 + col + 32], b);
  }
  float dv = dinv[n0 + nd];
  Y[(size_t)(n0 + nd) * 64 + col] = (_Float16)(dv * fmaxf(a, 0.f));
  Y[(size_t)(n0 + nd) * 64 + col + 32] = (_Float16)(dv * fmaxf(b, 0.f));
}

// ------- gath64: gather(x2 f16, 128 B/row) -> z3 (true scale) as f16 -------
__launch_bounds__(256)
__global__ void k_gath64(const _Float16* __restrict__ H, const int* __restrict__ esrc,
                         const int* __restrict__ row_start, const float* __restrict__ dinv,
                         _Float16* __restrict__ Zh) {
  int t = threadIdx.x;
  int n = blockIdx.x * 4 + (t >> 6);
  int fg = t & 15, way = (t >> 4) & 3;
  const half4* H4 = reinterpret_cast<const half4*>(H);
  float4 acc = make_float4(0.f, 0.f, 0.f, 0.f);
  if (way == 0) {
    half4 h = H4[(size_t)n * 16 + fg];
    acc.x = 2.f * (float)h[0]; acc.y = 2.f * (float)h[1];
    acc.z = 2.f * (float)h[2]; acc.w = 2.f * (float)h[3];
  }
  int end = row_start[n + 1];
  int i = row_start[n] + way;
  for (; i + 4 < end; i += 8) {
    int s0 = esrc[i], s1 = esrc[i + 4];
    half4 a = H4[(size_t)s0 * 16 + fg];
    half4 b = H4[(size_t)s1 * 16 + fg];
    acc.x += (float)a[0] + (float)b[0];
    acc.y += (float)a[1] + (float)b[1];
    acc.z += (float)a[2] + (float)b[2];
    acc.w += (float)a[3] + (float)b[3];
  }
  if (i < end) {
    int s = esrc[i];
    half4 a = H4[(size_t)s * 16 + fg];
    acc.x += (float)a[0]; acc.y += (float)a[1];
    acc.z += (float)a[2]; acc.w += (float)a[3];
  }
  acc.x += __shfl_xor(acc.x, 16); acc.y += __shfl_xor(acc.y, 16);
  acc.z += __shfl_xor(acc.z, 16); acc.w += __shfl_xor(acc.w, 16);
  acc.x += __shfl_xor(acc.x, 32); acc.y += __shfl_xor(acc.y, 32);
  acc.z += __shfl_xor(acc.z, 32); acc.w += __shfl_xor(acc.w, 32);
  if (way == 0) {
    float dv = dinv[n];
    half4 hv;
    hv[0] = (_Float16)(dv * acc.x); hv[1] = (_Float16)(dv * acc.y);
    hv[2] = (_Float16)(dv * acc.z); hv[3] = (_Float16)(dv * acc.w);
    *reinterpret_cast<half4*>(Zh + (size_t)n * 64 + fg * 4) = hv;
  }
}

// ---- read half8, unscale by s, repack ----
__device__ inline half8 cvt8h(const _Float16* __restrict__ p, float s) {
  half8 v = *reinterpret_cast<const half8*>(p);
  half8 a;
#pragma unroll
  for (int i = 0; i < 8; ++i) a[i] = (_Float16)(s * (float)v[i]);
  return a;
}

// ------- MFMA decode: x3 = relu(z3@Wc3+bc3); out = c0 + [x3|x2|x1] @ Acat -------
__launch_bounds__(256)
__global__ void k_decode(const _Float16* __restrict__ z3h, const _Float16* __restrict__ X2h,
                         const _Float16* __restrict__ X1h, const float* __restrict__ rdinv,
                         const half8* __restrict__ W3pk, const half8* __restrict__ Apk,
                         const float* __restrict__ bc3, const float* __restrict__ c0,
                         float* __restrict__ out) {
  __shared__ _Float16 sX3[4][16][136];
  int t = threadIdx.x;
  int w = t >> 6, l = t & 63;
  int m16 = l & 15, g = l >> 4;
  int n0 = blockIdx.x * 64 + w * 16;
  int nrow = n0 + m16;

  f32x4v acc[8];
  // ---- Phase B: x3 = relu(z3 @ Wc3 + bc3), K=64 ----
#pragma unroll
  for (int nb = 0; nb < 8; ++nb) {
    float bv = bc3[nb * 16 + m16];
    acc[nb] = (f32x4v){bv, bv, bv, bv};
  }
#pragma unroll
  for (int kb = 0; kb < 2; ++kb) {
    half8 a = *reinterpret_cast<const half8*>(z3h + (size_t)nrow * 64 + kb * 32 + g * 8);
#pragma unroll
    for (int nb = 0; nb < 8; ++nb) {
      half8 b = W3pk[(kb * 8 + nb) * 64 + l];
      acc[nb] = __builtin_amdgcn_mfma_f32_16x16x32_f16(a, b, acc[nb], 0, 0, 0);
    }
  }
#pragma unroll
  for (int nb = 0; nb < 8; ++nb)
#pragma unroll
    for (int r = 0; r < 4; ++r)
      sX3[w][g * 4 + r][nb * 16 + m16] = (_Float16)fmaxf(acc[nb][r], 0.0f);
  __syncthreads();

  // ---- Phase C: out = c0 + [x3|x2|x1] @ Acat, K=224 ----
  float rd = rdinv[nrow];
#pragma unroll
  for (int nb = 0; nb < 8; ++nb) {
    float cv = c0[nb * 16 + m16];
    acc[nb] = (f32x4v){cv, cv, cv, cv};
  }
#pragma unroll
  for (int kb = 0; kb < 7; ++kb) {
    half8 a;
    if (kb < 4)
      a = *reinterpret_cast<const half8*>(&sX3[w][m16][kb * 32 + g * 8]);
    else if (kb < 6)
      a = cvt8h(X2h + (size_t)nrow * 64 + (kb - 4) * 32 + g * 8, rd);
    else
      a = cvt8h(X1h + (size_t)nrow * 32 + g * 8, rd);
#pragma unroll
    for (int nb = 0; nb < 8; ++nb) {
      half8 b = Apk[(kb * 8 + nb) * 64 + l];
      acc[nb] = __builtin_amdgcn_mfma_f32_16x16x32_f16(a, b, acc[nb], 0, 0, 0);
    }
  }
#pragma unroll
  for (int nb = 0; nb < 8; ++nb)
#pragma unroll
    for (int r = 0; r < 4; ++r) {
      int n = n0 + g * 4 + r;
      if (n < NN) out[(size_t)n * 128 + nb * 16 + m16] = acc[nb][r];
    }
}

extern "C" void kernel_launch(void* const* d_in, const int* in_sizes, int n_in,
                              void* d_out, int out_size, void* d_ws, size_t ws_size,
                              hipStream_t stream) {
  const float* x   = (const float*)d_in[0];
  const int* ei    = (const int*)d_in[1];
  const int* srcv  = ei;
  const int* dstv  = ei + NE;
  const float* w1  = (const float*)d_in[2];
  const float* b1  = (const float*)d_in[3];
  const float* fw1 = (const float*)d_in[4];
  const float* fb1 = (const float*)d_in[5];
  const float* w2  = (const float*)d_in[6];
  const float* b2  = (const float*)d_in[7];
  const float* fw2 = (const float*)d_in[8];
  const float* fb2 = (const float*)d_in[9];
  const float* w3  = (const float*)d_in[10];
  const float* b3  = (const float*)d_in[11];
  const float* fw3 = (const float*)d_in[12];
  const float* fb3 = (const float*)d_in[13];
  const float* wd1 = (const float*)d_in[14];
  const float* bd1 = (const float*)d_in[15];
  const float* wd2 = (const float*)d_in[16];
  const float* bd2 = (const float*)d_in[17];
  const float* wd3 = (const float*)d_in[18];
  const float* bd3 = (const float*)d_in[19];
  const float* ws1 = (const float*)d_in[20];
  const float* bs1 = (const float*)d_in[21];
  const float* ws2 = (const float*)d_in[22];
  const float* bs2 = (const float*)d_in[23];
  const float* wf  = (const float*)d_in[24];
  const float* bf  = (const float*)d_in[25];

  float* fp = (float*)d_ws;
  float* dinv = fp;                       // 50176
  float* rdinv= dinv + 50176;             // 50176
  float* h1   = rdinv + 50176;            // 50048*32 f32; later overlaid by z3h (f16)
  _Float16* x1h = (_Float16*)(h1 + 1601536);   // 50048*32 halves = 800768 floats
  _Float16* x2h = x1h + 1601536;               // 50048*64 halves = 1601536 floats
  float* Wc2  = (float*)(x2h + 3203072);  // 2048
  float* Wc3  = Wc2 + 2048;               // 8192
  float* bc1  = Wc3 + 8192;               // 64
  float* bc2  = bc1 + 64;                 // 64
  float* bc3  = bc2 + 64;                 // 128
  float* G    = bc3 + 128;                // 16384
  float* Hm   = G + 16384;                // 16384
  float* A3   = Hm + 16384;               // 16384 } Acat = A3|A2|A1 [224][128]
  float* A2   = A3 + 16384;               // 8192  }
  float* A1   = A2 + 8192;                // 4096  }
  float* c0   = A1 + 4096;                // 256
  _Float16* W3pk = (_Float16*)(c0 + 256); // 8192 halves
  _Float16* Apk  = W3pk + 8192;           // 28672 halves
  int* ip     = (int*)(Apk + 28672);
  int* esrc   = ip;                       // 800000 int (final CSR src list)
  int2* epk2  = (int2*)(esrc + 800000);   // 800000 int2 (bucket temp)
  int* deg    = (int*)(epk2 + 800000);    // 50176
  int* row_start = deg + 50176;           // 50176 (NN+1 used)
  int* blksum = row_start + 50176;        // 256
  int* blkoff = blksum + 256;             // 256
  int* bcur   = blkoff + 256;             // 256

  _Float16* z3h = (_Float16*)h1;          // overlay: h1 dead after k_fuse1
  float* outp = (float*)d_out;

  // ---- CSR build (two-pass coalesced partition) ----
  k_zero<<<NBLK, 256, 0, stream>>>(deg);
  k_hist<<<(NE + 255) / 256, 256, 0, stream>>>(dstv, deg);
  k_blksum<<<NBLK, 256, 0, stream>>>(deg, blksum);
  k_blkscan<<<1, 256, 0, stream>>>(blksum, blkoff, bcur);
  k_scan3<<<NBLK, 256, 0, stream>>>(deg, blkoff, row_start, dinv, rdinv);
  k_part1<<<(NE + 4095) / 4096, 256, 0, stream>>>(srcv, dstv, bcur, epk2);
  k_part2<<<NBLK, 256, 0, stream>>>(epk2, row_start, esrc);

  // ---- weight composition ----
  k_prep1<<<105, 256, 0, stream>>>(wd3, wf, w2, fw2, w3, fw3, b1, fw1, fb1,
                                   b2, fb2, b3, fb3, G, Wc2, Wc3, bc1, bc2, bc3);
  k_prep_HA1<<<80, 256, 0, stream>>>(wd2, G, ws2, Hm, A1);
  k_prep_A32c0<<<97, 256, 0, stream>>>(wd1, ws1, Hm, G, wf, bd1, bs1, bd2, bs2, bd3, bf,
                                       A3, A2, c0);
  k_prep_pack<<<18, 256, 0, stream>>>(Wc3, A3 /*Acat*/, W3pk, Apk);

  // ---- pipeline ----
  k_gemm1t<<<(NN + 127) / 128, 256, 0, stream>>>(x, w1, dinv, h1);
  k_fuse1<<<NN / 8, 256, 0, stream>>>(h1, esrc, row_start, dinv, fw1, bc1, x1h);
  k_fuse2<<<NN / 8, 256, 0, stream>>>(x1h, esrc, row_start, dinv, Wc2, bc2, x2h);
  k_gath64<<<NN / 4, 256, 0, stream>>>(x2h, esrc, row_start, dinv, z3h);
  k_decode<<<(NN + 63) / 64, 256, 0, stream>>>(z3h, x2h, x1h, rdinv, (const half8*)W3pk,
                                               (const half8*)Apk, bc3, c0, outp);
}

// Round 10
// 171.240 us; speedup vs baseline: 1.3917x; 1.1936x over previous
//
#include <hip/hip_runtime.h>

#define NN 50000
#define NE 800000
#define NBLK 196  // ceil(NN/256); also bucket count (256 nodes/bucket)

typedef _Float16 half8 __attribute__((ext_vector_type(8)));
typedef _Float16 half4 __attribute__((ext_vector_type(4)));
typedef float f32x4v __attribute__((ext_vector_type(4)));

// ---------------- CSR build (histogram-free, bucketed) ----------------
__global__ void k_zero2(int* __restrict__ bcnt) {
  bcnt[threadIdx.x] = 0;  // 256 >= NBLK
}

// per-block LDS bucket histogram -> global bucket counts (50K atomics total)
__launch_bounds__(256)
__global__ void k_bcount(const int* __restrict__ dstv, int* __restrict__ bcnt) {
  __shared__ int cnt[256];
  int t = threadIdx.x;
  int e0 = blockIdx.x * 4096;
  cnt[t] = 0;
  __syncthreads();
#pragma unroll
  for (int i = 0; i < 16; ++i) {
    int e = e0 + i * 256 + t;
    if (e < NE) atomicAdd(&cnt[dstv[e] >> 8], 1);
  }
  __syncthreads();
  if (cnt[t] > 0) atomicAdd(&bcnt[t], cnt[t]);
}

// scan bucket counts -> bucket_off (exclusive), bcur; bucket_off[NBLK]=NE; row_start[NN]=NE
__global__ void k_bscan(const int* __restrict__ bcnt, int* __restrict__ boff,
                        int* __restrict__ bcur, int* __restrict__ row_start) {
  __shared__ int s[256];
  int t = threadIdx.x;
  int v0 = (t < NBLK) ? bcnt[t] : 0;
  s[t] = v0;
  __syncthreads();
  for (int off = 1; off < 256; off <<= 1) {
    int v = (t >= off) ? s[t - off] : 0;
    __syncthreads();
    s[t] += v;
    __syncthreads();
  }
  int e = s[t] - v0;
  if (t < NBLK) { boff[t] = e; bcur[t] = e; }
  if (t == 0) { boff[NBLK] = NE; row_start[NN] = NE; }
}

// Pass 1: block-aggregated partition by dst>>8; packed u32 record (src | dlow<<16)
__launch_bounds__(256)
__global__ void k_part1(const int* __restrict__ srcv, const int* __restrict__ dstv,
                        int* __restrict__ bcur, unsigned int* __restrict__ epk2) {
  __shared__ int cnt[256];
  __shared__ int base[256];
  int t = threadIdx.x;
  int e0 = blockIdx.x * 4096;
  cnt[t] = 0;
  __syncthreads();
  unsigned int pk[16];
  int lo[16], bk[16];
  bool ok[16];
#pragma unroll
  for (int i = 0; i < 16; ++i) {
    int e = e0 + i * 256 + t;
    ok[i] = (e < NE);
    if (ok[i]) {
      int s = srcv[e], d = dstv[e];
      bk[i] = d >> 8;
      pk[i] = (unsigned int)s | ((unsigned int)(d & 255) << 16);
      lo[i] = atomicAdd(&cnt[bk[i]], 1);
    }
  }
  __syncthreads();
  int c = cnt[t];
  if (c > 0) base[t] = atomicAdd(&bcur[t], c);
  __syncthreads();
#pragma unroll
  for (int i = 0; i < 16; ++i)
    if (ok[i]) epk2[base[bk[i]] + lo[i]] = pk[i];
}

// Pass 2: one block per bucket; per-node degree count + local scan -> row_start/dinv/rdinv,
// then exact placement into esrc (u16). All traffic bucket-local (L2-resident).
__launch_bounds__(256)
__global__ void k_part2c(const unsigned int* __restrict__ epk2, const int* __restrict__ boff,
                         int* __restrict__ row_start, float* __restrict__ dinv,
                         float* __restrict__ rdinv, unsigned short* __restrict__ esrc) {
  __shared__ int cnt[256];
  __shared__ int cur[256];
  __shared__ int ss[256];
  int t = threadIdx.x;
  int b = blockIdx.x;
  int rs0 = boff[b], rs1 = boff[b + 1];
  cnt[t] = 0;
  __syncthreads();
  for (int i = rs0 + t; i < rs1; i += 256) {
    unsigned int p = epk2[i];
    atomicAdd(&cnt[(p >> 16) & 255], 1);
  }
  __syncthreads();
  int d = cnt[t];
  ss[t] = d;
  __syncthreads();
  for (int off = 1; off < 256; off <<= 1) {
    int v = (t >= off) ? ss[t - off] : 0;
    __syncthreads();
    ss[t] += v;
    __syncthreads();
  }
  int rs = rs0 + ss[t] - d;
  int node = b * 256 + t;
  if (node < NN) {
    row_start[node] = rs;
    float df = (float)d + 2.0f;
    dinv[node] = rsqrtf(df);
    rdinv[node] = sqrtf(df);
  }
  cur[t] = rs;
  __syncthreads();
  for (int i = rs0 + t; i < rs1; i += 256) {
    unsigned int p = epk2[i];
    int dl = (p >> 16) & 255;
    int tgt = atomicAdd(&cur[dl], 1);
    esrc[tgt] = (unsigned short)(p & 0xFFFFu);
  }
}

// ------- weight composition: G[128][128] + {Wc2, Wc3, bc1, bc2, bc3} merged -------
__global__ void k_prep1(const float* __restrict__ wd3, const float* __restrict__ wf,
                        const float* __restrict__ w2, const float* __restrict__ fw2,
                        const float* __restrict__ w3, const float* __restrict__ fw3,
                        const float* __restrict__ b1, const float* __restrict__ fw1,
                        const float* __restrict__ fb1,
                        const float* __restrict__ b2, const float* __restrict__ fb2,
                        const float* __restrict__ b3, const float* __restrict__ fb3,
                        float* __restrict__ G,
                        float* __restrict__ Wc2, float* __restrict__ Wc3,
                        float* __restrict__ bc1, float* __restrict__ bc2,
                        float* __restrict__ bc3) {
  int id = blockIdx.x * 256 + threadIdx.x;
  if (id < 16384) {                      // G[c*4+l, k]
    int k = id & 127, r = id >> 7;
    int c = r >> 2, l = r & 3;
    float s = 0.f;
    for (int o = 0; o < 32; ++o) {
      s = fmaf(wd3[c * 64 + o * 2 + 0], wf[(o * 8 + 2 * l + 0) * 128 + k], s);
      s = fmaf(wd3[c * 64 + o * 2 + 1], wf[(o * 8 + 2 * l + 1) * 128 + k], s);
    }
    G[r * 128 + k] = s;
    return;
  }
  int id2 = id - 16384;
  if (id2 < 2048) {                      // Wc2 [32,64]
    int c = id2 >> 6, k = id2 & 63;
    float s = 0.f;
    for (int j = 0; j < 64; ++j) s = fmaf(w2[c * 64 + j], fw2[j * 64 + k], s);
    Wc2[id2] = s;
  } else if (id2 < 10240) {              // Wc3 [64,128]
    int idx = id2 - 2048;
    int c = idx >> 7, k = idx & 127;
    float s = 0.f;
    for (int j = 0; j < 128; ++j) s = fmaf(w3[c * 128 + j], fw3[j * 128 + k], s);
    Wc3[idx] = s;
  } else if (id2 < 10272) {              // bc1 [32]
    int k = id2 - 10240;
    float s = fb1[k];
    for (int j = 0; j < 32; ++j) s = fmaf(b1[j], fw1[j * 32 + k], s);
    bc1[k] = s;
  } else if (id2 < 10336) {              // bc2 [64]
    int k = id2 - 10272;
    float s = fb2[k];
    for (int j = 0; j < 64; ++j) s = fmaf(b2[j], fw2[j * 64 + k], s);
    bc2[k] = s;
  } else if (id2 < 10464) {              // bc3 [128]
    int k = id2 - 10336;
    float s = fb3[k];
    for (int j = 0; j < 128; ++j) s = fmaf(b3[j], fw3[j * 128 + k], s);
    bc3[k] = s;
  }
}

__global__ void k_prep_HA1(const float* __restrict__ wd2, const float* __restrict__ G,
                           const float* __restrict__ ws2,
                           float* __restrict__ Hm, float* __restrict__ A1) {
  int id = blockIdx.x * 256 + threadIdx.x;
  if (id < 16384) {
    int k = id & 127, r = id >> 7;
    int c = r >> 1, l = r & 1;
    float s = 0.f;
    for (int o = 0; o < 32; ++o) {
      s = fmaf(wd2[c * 64 + o * 2 + 0], G[(o * 4 + 2 * l + 0) * 128 + k], s);
      s = fmaf(wd2[c * 64 + o * 2 + 1], G[(o * 4 + 2 * l + 1) * 128 + k], s);
    }
    Hm[r * 128 + k] = s;
  } else if (id < 16384 + 4096) {
    int idx = id - 16384;
    int k = idx & 127, c = idx >> 7;   // c < 32
    float s = 0.f;
    for (int o = 0; o < 32; ++o) {
      float g = G[(4 * o) * 128 + k] + G[(4 * o + 1) * 128 + k] +
                G[(4 * o + 2) * 128 + k] + G[(4 * o + 3) * 128 + k];
      s = fmaf(ws2[c * 32 + o], g, s);
    }
    A1[c * 128 + k] = s;
  }
}

__global__ void k_prep_A32c0(const float* __restrict__ wd1, const float* __restrict__ ws1,
                             const float* __restrict__ Hm, const float* __restrict__ G,
                             const float* __restrict__ wf,
                             const float* __restrict__ bd1, const float* __restrict__ bs1,
                             const float* __restrict__ bd2, const float* __restrict__ bs2,
                             const float* __restrict__ bd3, const float* __restrict__ bf,
                             float* __restrict__ A3, float* __restrict__ A2,
                             float* __restrict__ c0) {
  int id = blockIdx.x * 256 + threadIdx.x;
  if (id < 16384) {
    int k = id & 127, c = id >> 7;
    float s = 0.f;
    for (int j = 0; j < 128; ++j) s = fmaf(wd1[c * 128 + j], Hm[j * 128 + k], s);
    A3[c * 128 + k] = s;
  } else if (id < 16384 + 8192) {
    int idx = id - 16384;
    int k = idx & 127, c = idx >> 7;   // c < 64
    float s = 0.f;
    for (int o = 0; o < 64; ++o)
      s = fmaf(ws1[c * 64 + o], Hm[(2 * o) * 128 + k] + Hm[(2 * o + 1) * 128 + k], s);
    A2[c * 128 + k] = s;
  } else if (id < 16384 + 8192 + 128) {
    int k = id - 16384 - 8192;
    float s = bf[k];
    for (int o = 0; o < 64; ++o) {
      float b = bd1[o] + bs1[o];
      s = fmaf(b, Hm[(o * 2) * 128 + k] + Hm[(o * 2 + 1) * 128 + k], s);
    }
    for (int o = 0; o < 32; ++o) {
      float b = bd2[o] + bs2[o];
      float g = G[(o * 4) * 128 + k] + G[(o * 4 + 1) * 128 + k] +
                G[(o * 4 + 2) * 128 + k] + G[(o * 4 + 3) * 128 + k];
      s = fmaf(b, g, s);
    }
    for (int o = 0; o < 32; ++o) {
      float w8 = 0.f;
      for (int j = 0; j < 8; ++j) w8 += wf[(o * 8 + j) * 128 + k];
      s = fmaf(bd3[o], w8, s);
    }
    c0[k] = s;
  }
}

// -------- pack B fragments (f16) for mfma_f32_16x16x32_f16 --------
__global__ void k_prep_pack(const float* __restrict__ Wc3, const float* __restrict__ Acat,
                            _Float16* __restrict__ W3pk, _Float16* __restrict__ Apk) {
  int id = blockIdx.x * 256 + threadIdx.x;
  if (id < 1024) {
    int l = id & 63, nb = (id >> 6) & 7, kb = id >> 9;
    int kbase = kb * 32 + ((l >> 4) << 3);
    int col = nb * 16 + (l & 15);
#pragma unroll
    for (int j = 0; j < 8; ++j)
      W3pk[id * 8 + j] = (_Float16)Wc3[(kbase + j) * 128 + col];
  } else if (id < 1024 + 3584) {
    int idx = id - 1024;
    int l = idx & 63, nb = (idx >> 6) & 7, kb = idx >> 9;
    int kbase = kb * 32 + ((l >> 4) << 3);
    int col = nb * 16 + (l & 15);
#pragma unroll
    for (int j = 0; j < 8; ++j)
      Apk[idx * 8 + j] = (_Float16)Acat[(kbase + j) * 128 + col];
  }
}

// ---------------- layer-1: h1' = dinv[n] * (x @ w1) -> f16, register-tiled ----------
__launch_bounds__(256)
__global__ void k_gemm1t(const float* __restrict__ X, const float* __restrict__ W,
                         const float* __restrict__ dinv, _Float16* __restrict__ Yh) {
  __shared__ float sW[128 * 32];
  __shared__ float sXc[128 * 33];
  int t = threadIdx.x;
  int n0 = blockIdx.x * 128;
#pragma unroll
  for (int it = 0; it < 4; ++it) {
    int idx = t + it * 256;
    int kr = idx >> 3, c4 = (idx & 7) * 4;
    *reinterpret_cast<float4*>(&sW[kr * 32 + c4]) =
        *reinterpret_cast<const float4*>(&W[kr * 32 + c4]);
  }
  int rg = t >> 3;
  int cg = t & 7;
  float acc[4][4];
#pragma unroll
  for (int r = 0; r < 4; ++r)
#pragma unroll
    for (int c = 0; c < 4; ++c) acc[r][c] = 0.f;

  for (int ch = 0; ch < 4; ++ch) {
    __syncthreads();
#pragma unroll
    for (int it = 0; it < 4; ++it) {
      int idx = t + it * 256;
      int row = idx & 127, k4 = (idx >> 7) * 4;
      int n = n0 + row;
      float4 v = make_float4(0.f, 0.f, 0.f, 0.f);
      if (n < NN) v = *reinterpret_cast<const float4*>(&X[(size_t)n * 128 + ch * 32 + k4]);
      sXc[row * 33 + k4 + 0] = v.x;
      sXc[row * 33 + k4 + 1] = v.y;
      sXc[row * 33 + k4 + 2] = v.z;
      sXc[row * 33 + k4 + 3] = v.w;
    }
    __syncthreads();
#pragma unroll
    for (int k = 0; k < 32; ++k) {
      float4 w = *reinterpret_cast<const float4*>(&sW[(ch * 32 + k) * 32 + cg * 4]);
#pragma unroll
      for (int r = 0; r < 4; ++r) {
        float xv = sXc[(rg * 4 + r) * 33 + k];
        acc[r][0] = fmaf(xv, w.x, acc[r][0]);
        acc[r][1] = fmaf(xv, w.y, acc[r][1]);
        acc[r][2] = fmaf(xv, w.z, acc[r][2]);
        acc[r][3] = fmaf(xv, w.w, acc[r][3]);
      }
    }
  }
#pragma unroll
  for (int r = 0; r < 4; ++r) {
    int n = n0 + rg * 4 + r;
    if (n < NN) {
      float dv = dinv[n];
      half4 hv;
      hv[0] = (_Float16)(dv * acc[r][0]); hv[1] = (_Float16)(dv * acc[r][1]);
      hv[2] = (_Float16)(dv * acc[r][2]); hv[3] = (_Float16)(dv * acc[r][3]);
      *reinterpret_cast<half4*>(&Yh[(size_t)n * 32 + cg * 4]) = hv;
    }
  }
}

// ---- coef-free 4-way gather sum, f16 rows F=32 ----
__device__ inline float4 gsum32h(const half4* __restrict__ H4,
                                 const unsigned short* __restrict__ esrc,
                                 const int* __restrict__ row_start,
                                 int n, int fg, int way) {
  float4 acc = make_float4(0.f, 0.f, 0.f, 0.f);
  if (way == 0) {
    half4 h = H4[(size_t)n * 8 + fg];
    acc.x = 2.f * (float)h[0]; acc.y = 2.f * (float)h[1];
    acc.z = 2.f * (float)h[2]; acc.w = 2.f * (float)h[3];
  }
  int end = row_start[n + 1];
  int i = row_start[n] + way;
  for (; i + 4 < end; i += 8) {
    int s0 = esrc[i], s1 = esrc[i + 4];
    half4 a = H4[(size_t)s0 * 8 + fg];
    half4 b = H4[(size_t)s1 * 8 + fg];
    acc.x += (float)a[0] + (float)b[0];
    acc.y += (float)a[1] + (float)b[1];
    acc.z += (float)a[2] + (float)b[2];
    acc.w += (float)a[3] + (float)b[3];
  }
  if (i < end) {
    int s = esrc[i];
    half4 a = H4[(size_t)s * 8 + fg];
    acc.x += (float)a[0]; acc.y += (float)a[1];
    acc.z += (float)a[2]; acc.w += (float)a[3];
  }
  acc.x += __shfl_xor(acc.x, 8);  acc.y += __shfl_xor(acc.y, 8);
  acc.z += __shfl_xor(acc.z, 8);  acc.w += __shfl_xor(acc.w, 8);
  acc.x += __shfl_xor(acc.x, 16); acc.y += __shfl_xor(acc.y, 16);
  acc.z += __shfl_xor(acc.z, 16); acc.w += __shfl_xor(acc.w, 16);
  return acc;
}

// ---- fuse1: gather(h1 f16) + GEMM 32->32 + relu -> x1 (f16, pre-scaled) ----
__launch_bounds__(256)
__global__ void k_fuse1(const _Float16* __restrict__ H, const unsigned short* __restrict__ esrc,
                        const int* __restrict__ row_start, const float* __restrict__ dinv,
                        const float* __restrict__ W, const float* __restrict__ bias,
                        _Float16* __restrict__ Y) {
  __shared__ float sZT[32][9];   // [feat][node], z = dinv*S
  __shared__ float sW[32 * 32];
  int t = threadIdx.x;
  int n0 = blockIdx.x * 8;
  {
    int kr = t >> 3, c4 = (t & 7) * 4;
    *reinterpret_cast<float4*>(&sW[kr * 32 + c4]) =
        *reinterpret_cast<const float4*>(&W[kr * 32 + c4]);
  }
  int node = t >> 5, fg = t & 7, way = (t >> 3) & 3;
  int n = n0 + node;
  float4 z = gsum32h(reinterpret_cast<const half4*>(H), esrc, row_start, n, fg, way);
  if (way == 0) {
    float dv = dinv[n];
    sZT[fg * 4 + 0][node] = dv * z.x;
    sZT[fg * 4 + 1][node] = dv * z.y;
    sZT[fg * 4 + 2][node] = dv * z.z;
    sZT[fg * 4 + 3][node] = dv * z.w;
  }
  __syncthreads();
  int nd = t >> 5, col = t & 31;
  float a = bias[col];
#pragma unroll
  for (int k = 0; k < 32; ++k) a = fmaf(sZT[k][nd], sW[k * 32 + col], a);
  Y[(size_t)(n0 + nd) * 32 + col] = (_Float16)(dinv[n0 + nd] * fmaxf(a, 0.f));
}

// ---- fuse2: gather(x1 f16) + GEMM 32->64 + relu -> x2 (f16, pre-scaled) ----
__launch_bounds__(256)
__global__ void k_fuse2(const _Float16* __restrict__ H, const unsigned short* __restrict__ esrc,
                        const int* __restrict__ row_start, const float* __restrict__ dinv,
                        const float* __restrict__ W, const float* __restrict__ bias,
                        _Float16* __restrict__ Y) {
  __shared__ float sZT[32][9];
  __shared__ float sW[32 * 64];
  int t = threadIdx.x;
  int n0 = blockIdx.x * 8;
#pragma unroll
  for (int it = 0; it < 2; ++it) {
    int idx = t + it * 256;
    int kr = idx >> 4, c4 = (idx & 15) * 4;
    *reinterpret_cast<float4*>(&sW[kr * 64 + c4]) =
        *reinterpret_cast<const float4*>(&W[kr * 64 + c4]);
  }
  int node = t >> 5, fg = t & 7, way = (t >> 3) & 3;
  int n = n0 + node;
  float4 z = gsum32h(reinterpret_cast<const half4*>(H), esrc, row_start, n, fg, way);
  if (way == 0) {
    float dv = dinv[n];
    sZT[fg * 4 + 0][node] = dv * z.x;
    sZT[fg * 4 + 1][node] = dv * z.y;
    sZT[fg * 4 + 2][node] = dv * z.z;
    sZT[fg * 4 + 3][node] = dv * z.w;
  }
  __syncthreads();
  int nd = t >> 5, col = t & 31;
  float a = bias[col], b = bias[col + 32];
#pragma unroll
  for (int k = 0; k < 32; ++k) {
    float zv = sZT[k][nd];
    a = fmaf(zv, sW[k * 64 + col], a);
    b = fmaf(zv, sW[k * 64 + col + 32], b);
  }
  float dv = dinv[n0 + nd];
  Y[(size_t)(n0 + nd) * 64 + col] = (_Float16)(dv * fmaxf(a, 0.f));
  Y[(size_t)(n0 + nd) * 64 + col + 32] = (_Float16)(dv * fmaxf(b, 0.f));
}

// ------- gath64: gather(x2 f16, 128 B/row) -> z3 (true scale) as f16 -------
__launch_bounds__(256)
__global__ void k_gath64(const _Float16* __restrict__ H, const unsigned short* __restrict__ esrc,
                         const int* __restrict__ row_start, const float* __restrict__ dinv,
                         _Float16* __restrict__ Zh) {
  int t = threadIdx.x;
  int n = blockIdx.x * 4 + (t >> 6);
  int fg = t & 15, way = (t >> 4) & 3;
  const half4* H4 = reinterpret_cast<const half4*>(H);
  float4 acc = make_float4(0.f, 0.f, 0.f, 0.f);
  if (way == 0) {
    half4 h = H4[(size_t)n * 16 + fg];
    acc.x = 2.f * (float)h[0]; acc.y = 2.f * (float)h[1];
    acc.z = 2.f * (float)h[2]; acc.w = 2.f * (float)h[3];
  }
  int end = row_start[n + 1];
  int i = row_start[n] + way;
  for (; i + 4 < end; i += 8) {
    int s0 = esrc[i], s1 = esrc[i + 4];
    half4 a = H4[(size_t)s0 * 16 + fg];
    half4 b = H4[(size_t)s1 * 16 + fg];
    acc.x += (float)a[0] + (float)b[0];
    acc.y += (float)a[1] + (float)b[1];
    acc.z += (float)a[2] + (float)b[2];
    acc.w += (float)a[3] + (float)b[3];
  }
  if (i < end) {
    int s = esrc[i];
    half4 a = H4[(size_t)s * 16 + fg];
    acc.x += (float)a[0]; acc.y += (float)a[1];
    acc.z += (float)a[2]; acc.w += (float)a[3];
  }
  acc.x += __shfl_xor(acc.x, 16); acc.y += __shfl_xor(acc.y, 16);
  acc.z += __shfl_xor(acc.z, 16); acc.w += __shfl_xor(acc.w, 16);
  acc.x += __shfl_xor(acc.x, 32); acc.y += __shfl_xor(acc.y, 32);
  acc.z += __shfl_xor(acc.z, 32); acc.w += __shfl_xor(acc.w, 32);
  if (way == 0) {
    float dv = dinv[n];
    half4 hv;
    hv[0] = (_Float16)(dv * acc.x); hv[1] = (_Float16)(dv * acc.y);
    hv[2] = (_Float16)(dv * acc.z); hv[3] = (_Float16)(dv * acc.w);
    *reinterpret_cast<half4*>(Zh + (size_t)n * 64 + fg * 4) = hv;
  }
}

// ---- read half8, unscale by s, repack ----
__device__ inline half8 cvt8h(const _Float16* __restrict__ p, float s) {
  half8 v = *reinterpret_cast<const half8*>(p);
  half8 a;
#pragma unroll
  for (int i = 0; i < 8; ++i) a[i] = (_Float16)(s * (float)v[i]);
  return a;
}

// ------- MFMA decode: x3 = relu(z3@Wc3+bc3); out = c0 + [x3|x2|x1] @ Acat -------
__launch_bounds__(256)
__global__ void k_decode(const _Float16* __restrict__ z3h, const _Float16* __restrict__ X2h,
                         const _Float16* __restrict__ X1h, const float* __restrict__ rdinv,
                         const half8* __restrict__ W3pk, const half8* __restrict__ Apk,
                         const float* __restrict__ bc3, const float* __restrict__ c0,
                         float* __restrict__ out) {
  __shared__ _Float16 sX3[4][16][136];
  int t = threadIdx.x;
  int w = t >> 6, l = t & 63;
  int m16 = l & 15, g = l >> 4;
  int n0 = blockIdx.x * 64 + w * 16;
  int nrow = n0 + m16;

  f32x4v acc[8];
  // ---- Phase B: x3 = relu(z3 @ Wc3 + bc3), K=64 ----
#pragma unroll
  for (int nb = 0; nb < 8; ++nb) {
    float bv = bc3[nb * 16 + m16];
    acc[nb] = (f32x4v){bv, bv, bv, bv};
  }
#pragma unroll
  for (int kb = 0; kb < 2; ++kb) {
    half8 a = *reinterpret_cast<const half8*>(z3h + (size_t)nrow * 64 + kb * 32 + g * 8);
#pragma unroll
    for (int nb = 0; nb < 8; ++nb) {
      half8 b = W3pk[(kb * 8 + nb) * 64 + l];
      acc[nb] = __builtin_amdgcn_mfma_f32_16x16x32_f16(a, b, acc[nb], 0, 0, 0);
    }
  }
#pragma unroll
  for (int nb = 0; nb < 8; ++nb)
#pragma unroll
    for (int r = 0; r < 4; ++r)
      sX3[w][g * 4 + r][nb * 16 + m16] = (_Float16)fmaxf(acc[nb][r], 0.0f);
  __syncthreads();

  // ---- Phase C: out = c0 + [x3|x2|x1] @ Acat, K=224 ----
  float rd = rdinv[nrow];
#pragma unroll
  for (int nb = 0; nb < 8; ++nb) {
    float cv = c0[nb * 16 + m16];
    acc[nb] = (f32x4v){cv, cv, cv, cv};
  }
#pragma unroll
  for (int kb = 0; kb < 7; ++kb) {
    half8 a;
    if (kb < 4)
      a = *reinterpret_cast<const half8*>(&sX3[w][m16][kb * 32 + g * 8]);
    else if (kb < 6)
      a = cvt8h(X2h + (size_t)nrow * 64 + (kb - 4) * 32 + g * 8, rd);
    else
      a = cvt8h(X1h + (size_t)nrow * 32 + g * 8, rd);
#pragma unroll
    for (int nb = 0; nb < 8; ++nb) {
      half8 b = Apk[(kb * 8 + nb) * 64 + l];
      acc[nb] = __builtin_amdgcn_mfma_f32_16x16x32_f16(a, b, acc[nb], 0, 0, 0);
    }
  }
#pragma unroll
  for (int nb = 0; nb < 8; ++nb)
#pragma unroll
    for (int r = 0; r < 4; ++r) {
      int n = n0 + g * 4 + r;
      if (n < NN) out[(size_t)n * 128 + nb * 16 + m16] = acc[nb][r];
    }
}

extern "C" void kernel_launch(void* const* d_in, const int* in_sizes, int n_in,
                              void* d_out, int out_size, void* d_ws, size_t ws_size,
                              hipStream_t stream) {
  const float* x   = (const float*)d_in[0];
  const int* ei    = (const int*)d_in[1];
  const int* srcv  = ei;
  const int* dstv  = ei + NE;
  const float* w1  = (const float*)d_in[2];
  const float* b1  = (const float*)d_in[3];
  const float* fw1 = (const float*)d_in[4];
  const float* fb1 = (const float*)d_in[5];
  const float* w2  = (const float*)d_in[6];
  const float* b2  = (const float*)d_in[7];
  const float* fw2 = (const float*)d_in[8];
  const float* fb2 = (const float*)d_in[9];
  const float* w3  = (const float*)d_in[10];
  const float* b3  = (const float*)d_in[11];
  const float* fw3 = (const float*)d_in[12];
  const float* fb3 = (const float*)d_in[13];
  const float* wd1 = (const float*)d_in[14];
  const float* bd1 = (const float*)d_in[15];
  const float* wd2 = (const float*)d_in[16];
  const float* bd2 = (const float*)d_in[17];
  const float* wd3 = (const float*)d_in[18];
  const float* bd3 = (const float*)d_in[19];
  const float* ws1 = (const float*)d_in[20];
  const float* bs1 = (const float*)d_in[21];
  const float* ws2 = (const float*)d_in[22];
  const float* bs2 = (const float*)d_in[23];
  const float* wf  = (const float*)d_in[24];
  const float* bf  = (const float*)d_in[25];

  float* fp = (float*)d_ws;
  float* dinv = fp;                         // 50176
  float* rdinv= dinv + 50176;               // 50176
  _Float16* h1h = (_Float16*)(rdinv + 50176);  // 50048*32 halves = 800768 f
  _Float16* x1h = h1h + 1601536;               // 50048*32 halves
  _Float16* x2h = x1h + 1601536;               // 50048*64 halves = 1601536 f
  _Float16* z3h = x2h + 3203072;               // 50048*64 halves
  float* Wc2  = (float*)(z3h + 3203072);    // 2048
  float* Wc3  = Wc2 + 2048;                 // 8192
  float* bc1  = Wc3 + 8192;                 // 64
  float* bc2  = bc1 + 64;                   // 64
  float* bc3  = bc2 + 64;                   // 128
  float* G    = bc3 + 128;                  // 16384
  float* Hm   = G + 16384;                  // 16384
  float* A3   = Hm + 16384;                 // 16384 } Acat = A3|A2|A1 [224][128]
  float* A2   = A3 + 16384;                 // 8192  }
  float* A1   = A2 + 8192;                  // 4096  }
  float* c0   = A1 + 4096;                  // 256
  _Float16* W3pk = (_Float16*)(c0 + 256);   // 8192 halves
  _Float16* Apk  = W3pk + 8192;             // 28672 halves
  unsigned int* epk2 = (unsigned int*)(Apk + 28672);  // 800000 u32
  unsigned short* esrc = (unsigned short*)(epk2 + 800000); // 800000 u16
  int* ip     = (int*)(esrc + 800128);      // (pad to 4B align)
  int* row_start = ip;                      // 50176 (NN+1 used)
  int* bcnt   = row_start + 50176;          // 256
  int* boff   = bcnt + 256;                 // 257
  int* bcur   = boff + 260;                 // 256

  float* outp = (float*)d_out;

  // ---- CSR build (histogram-free bucketed partition) ----
  k_zero2<<<1, 256, 0, stream>>>(bcnt);
  k_bcount<<<(NE + 4095) / 4096, 256, 0, stream>>>(dstv, bcnt);
  k_bscan<<<1, 256, 0, stream>>>(bcnt, boff, bcur, row_start);
  k_part1<<<(NE + 4095) / 4096, 256, 0, stream>>>(srcv, dstv, bcur, epk2);
  k_part2c<<<NBLK, 256, 0, stream>>>(epk2, boff, row_start, dinv, rdinv, esrc);

  // ---- weight composition ----
  k_prep1<<<105, 256, 0, stream>>>(wd3, wf, w2, fw2, w3, fw3, b1, fw1, fb1,
                                   b2, fb2, b3, fb3, G, Wc2, Wc3, bc1, bc2, bc3);
  k_prep_HA1<<<80, 256, 0, stream>>>(wd2, G, ws2, Hm, A1);
  k_prep_A32c0<<<97, 256, 0, stream>>>(wd1, ws1, Hm, G, wf, bd1, bs1, bd2, bs2, bd3, bf,
                                       A3, A2, c0);
  k_prep_pack<<<18, 256, 0, stream>>>(Wc3, A3 /*Acat*/, W3pk, Apk);

  // ---- pipeline ----
  k_gemm1t<<<(NN + 127) / 128, 256, 0, stream>>>(x, w1, dinv, h1h);
  k_fuse1<<<NN / 8, 256, 0, stream>>>(h1h, esrc, row_start, dinv, fw1, bc1, x1h);
  k_fuse2<<<NN / 8, 256, 0, stream>>>(x1h, esrc, row_start, dinv, Wc2, bc2, x2h);
  k_gath64<<<NN / 4, 256, 0, stream>>>(x2h, esrc, row_start, dinv, z3h);
  k_decode<<<(NN + 63) / 64, 256, 0, stream>>>(z3h, x2h, x1h, rdinv, (const half8*)W3pk,
                                               (const half8*)Apk, bc3, c0, outp);
}

// Round 11
// 147.159 us; speedup vs baseline: 1.6194x; 1.1636x over previous
//
#include <hip/hip_runtime.h>

#define NN 50000
#define NE 800000
#define NBLK 196  // ceil(NN/256); bucket count (256 nodes/bucket); also edge-chunk blocks

typedef _Float16 half8 __attribute__((ext_vector_type(8)));
typedef _Float16 half4 __attribute__((ext_vector_type(4)));
typedef float f32x4v __attribute__((ext_vector_type(4)));

// =================== K1: bucket-count (atomic-free) + prep1 + w1 pack ===================
__launch_bounds__(256)
__global__ void k_u1(const int* __restrict__ dstv, int* __restrict__ bcnt2,
                     const float* __restrict__ wd3, const float* __restrict__ wf,
                     const float* __restrict__ w2, const float* __restrict__ fw2,
                     const float* __restrict__ w3, const float* __restrict__ fw3,
                     const float* __restrict__ b1, const float* __restrict__ fw1,
                     const float* __restrict__ fb1,
                     const float* __restrict__ b2, const float* __restrict__ fb2,
                     const float* __restrict__ b3, const float* __restrict__ fb3,
                     float* __restrict__ G,
                     float* __restrict__ Wc2, float* __restrict__ Wc3,
                     float* __restrict__ bc1, float* __restrict__ bc2,
                     float* __restrict__ bc3,
                     const float* __restrict__ w1, _Float16* __restrict__ W1pk) {
  __shared__ int cnt[256];
  int t = threadIdx.x;
  int b = blockIdx.x;
  if (b < NBLK) {  // ---- bucket count: per-block slot, no global atomics ----
    int e0 = b * 4096;
    cnt[t] = 0;
    __syncthreads();
#pragma unroll
    for (int i = 0; i < 16; ++i) {
      int e = e0 + i * 256 + t;
      if (e < NE) atomicAdd(&cnt[dstv[e] >> 8], 1);
    }
    __syncthreads();
    bcnt2[b * 256 + t] = cnt[t];
    return;
  }
  if (b < NBLK + 105) {  // ---- prep1: G + Wc2/Wc3/bc1/bc2/bc3 ----
    int id = (b - NBLK) * 256 + t;
    if (id < 16384) {                      // G[c*4+l, k]
      int k = id & 127, r = id >> 7;
      int c = r >> 2, l = r & 3;
      float s = 0.f;
      for (int o = 0; o < 32; ++o) {
        s = fmaf(wd3[c * 64 + o * 2 + 0], wf[(o * 8 + 2 * l + 0) * 128 + k], s);
        s = fmaf(wd3[c * 64 + o * 2 + 1], wf[(o * 8 + 2 * l + 1) * 128 + k], s);
      }
      G[r * 128 + k] = s;
      return;
    }
    int id2 = id - 16384;
    if (id2 < 2048) {                      // Wc2 [32,64]
      int c = id2 >> 6, k = id2 & 63;
      float s = 0.f;
      for (int j = 0; j < 64; ++j) s = fmaf(w2[c * 64 + j], fw2[j * 64 + k], s);
      Wc2[id2] = s;
    } else if (id2 < 10240) {              // Wc3 [64,128]
      int idx = id2 - 2048;
      int c = idx >> 7, k = idx & 127;
      float s = 0.f;
      for (int j = 0; j < 128; ++j) s = fmaf(w3[c * 128 + j], fw3[j * 128 + k], s);
      Wc3[idx] = s;
    } else if (id2 < 10272) {              // bc1 [32]
      int k = id2 - 10240;
      float s = fb1[k];
      for (int j = 0; j < 32; ++j) s = fmaf(b1[j], fw1[j * 32 + k], s);
      bc1[k] = s;
    } else if (id2 < 10336) {              // bc2 [64]
      int k = id2 - 10272;
      float s = fb2[k];
      for (int j = 0; j < 64; ++j) s = fmaf(b2[j], fw2[j * 64 + k], s);
      bc2[k] = s;
    } else if (id2 < 10464) {              // bc3 [128]
      int k = id2 - 10336;
      float s = fb3[k];
      for (int j = 0; j < 128; ++j) s = fmaf(b3[j], fw3[j * 128 + k], s);
      bc3[k] = s;
    }
    return;
  }
  // ---- pack w1 [128][32] fragments: frag (kb,nb) kb<4, nb<2 ----
#pragma unroll
  for (int it = 0; it < 2; ++it) {
    int id = t + it * 256;  // 0..511 = frag*64 + lane
    int l = id & 63, f = id >> 6;   // f = kb*2+nb
    int kb = f >> 1, nb = f & 1;
    int kbase = kb * 32 + ((l >> 4) << 3);
    int col = nb * 16 + (l & 15);
#pragma unroll
    for (int j = 0; j < 8; ++j)
      W1pk[id * 8 + j] = (_Float16)w1[(kbase + j) * 32 + col];
  }
}

// =================== K2: bucket scan + prep_HA1 ===================
__launch_bounds__(256)
__global__ void k_u2(const int* __restrict__ bcnt2, int* __restrict__ boff,
                     int* __restrict__ bcur, int* __restrict__ row_start,
                     const float* __restrict__ wd2, const float* __restrict__ G,
                     const float* __restrict__ ws2,
                     float* __restrict__ Hm, float* __restrict__ A1) {
  int t = threadIdx.x;
  int b = blockIdx.x;
  if (b == 0) {  // ---- sum per-block counts + exclusive scan ----
    __shared__ int s[256];
    int v0 = 0;
    if (t < NBLK)
      for (int blk = 0; blk < NBLK; ++blk) v0 += bcnt2[blk * 256 + t];
    s[t] = v0;
    __syncthreads();
    for (int off = 1; off < 256; off <<= 1) {
      int v = (t >= off) ? s[t - off] : 0;
      __syncthreads();
      s[t] += v;
      __syncthreads();
    }
    int e = s[t] - v0;
    if (t < NBLK) { boff[t] = e; bcur[t] = e; }
    if (t == 0) { boff[NBLK] = NE; row_start[NN] = NE; }
    return;
  }
  int id = (b - 1) * 256 + t;
  if (id < 16384) {
    int k = id & 127, r = id >> 7;
    int c = r >> 1, l = r & 1;
    float s = 0.f;
    for (int o = 0; o < 32; ++o) {
      s = fmaf(wd2[c * 64 + o * 2 + 0], G[(o * 4 + 2 * l + 0) * 128 + k], s);
      s = fmaf(wd2[c * 64 + o * 2 + 1], G[(o * 4 + 2 * l + 1) * 128 + k], s);
    }
    Hm[r * 128 + k] = s;
  } else if (id < 16384 + 4096) {
    int idx = id - 16384;
    int k = idx & 127, c = idx >> 7;   // c < 32
    float s = 0.f;
    for (int o = 0; o < 32; ++o) {
      float g = G[(4 * o) * 128 + k] + G[(4 * o + 1) * 128 + k] +
                G[(4 * o + 2) * 128 + k] + G[(4 * o + 3) * 128 + k];
      s = fmaf(ws2[c * 32 + o], g, s);
    }
    A1[c * 128 + k] = s;
  }
}

// =================== K3: partition pass 1 + prep_A32c0 ===================
__launch_bounds__(256)
__global__ void k_u3(const int* __restrict__ srcv, const int* __restrict__ dstv,
                     int* __restrict__ bcur, unsigned int* __restrict__ epk2,
                     const float* __restrict__ wd1, const float* __restrict__ ws1,
                     const float* __restrict__ Hm, const float* __restrict__ G,
                     const float* __restrict__ wf,
                     const float* __restrict__ bd1, const float* __restrict__ bs1,
                     const float* __restrict__ bd2, const float* __restrict__ bs2,
                     const float* __restrict__ bd3, const float* __restrict__ bf,
                     float* __restrict__ A3, float* __restrict__ A2,
                     float* __restrict__ c0) {
  __shared__ int cnt[256];
  __shared__ int base[256];
  int t = threadIdx.x;
  int b = blockIdx.x;
  if (b < NBLK) {  // ---- part1 ----
    int e0 = b * 4096;
    cnt[t] = 0;
    __syncthreads();
    unsigned int pk[16];
    int lo[16], bk[16];
    bool ok[16];
#pragma unroll
    for (int i = 0; i < 16; ++i) {
      int e = e0 + i * 256 + t;
      ok[i] = (e < NE);
      if (ok[i]) {
        int s = srcv[e], d = dstv[e];
        bk[i] = d >> 8;
        pk[i] = (unsigned int)s | ((unsigned int)(d & 255) << 16);
        lo[i] = atomicAdd(&cnt[bk[i]], 1);
      }
    }
    __syncthreads();
    int c = cnt[t];
    if (c > 0) base[t] = atomicAdd(&bcur[t], c);
    __syncthreads();
#pragma unroll
    for (int i = 0; i < 16; ++i)
      if (ok[i]) epk2[base[bk[i]] + lo[i]] = pk[i];
    return;
  }
  int id = (b - NBLK) * 256 + t;
  if (id < 16384) {
    int k = id & 127, c = id >> 7;
    float s = 0.f;
    for (int j = 0; j < 128; ++j) s = fmaf(wd1[c * 128 + j], Hm[j * 128 + k], s);
    A3[c * 128 + k] = s;
  } else if (id < 16384 + 8192) {
    int idx = id - 16384;
    int k = idx & 127, c = idx >> 7;   // c < 64
    float s = 0.f;
    for (int o = 0; o < 64; ++o)
      s = fmaf(ws1[c * 64 + o], Hm[(2 * o) * 128 + k] + Hm[(2 * o + 1) * 128 + k], s);
    A2[c * 128 + k] = s;
  } else if (id < 16384 + 8192 + 128) {
    int k = id - 16384 - 8192;
    float s = bf[k];
    for (int o = 0; o < 64; ++o) {
      float bb = bd1[o] + bs1[o];
      s = fmaf(bb, Hm[(o * 2) * 128 + k] + Hm[(o * 2 + 1) * 128 + k], s);
    }
    for (int o = 0; o < 32; ++o) {
      float bb = bd2[o] + bs2[o];
      float g = G[(o * 4) * 128 + k] + G[(o * 4 + 1) * 128 + k] +
                G[(o * 4 + 2) * 128 + k] + G[(o * 4 + 3) * 128 + k];
      s = fmaf(bb, g, s);
    }
    for (int o = 0; o < 32; ++o) {
      float w8 = 0.f;
      for (int j = 0; j < 8; ++j) w8 += wf[(o * 8 + j) * 128 + k];
      s = fmaf(bd3[o], w8, s);
    }
    c0[k] = s;
  }
}

// =================== K4: partition pass 2 (degrees+place) + B-fragment pack ===================
__launch_bounds__(256)
__global__ void k_u4(const unsigned int* __restrict__ epk2, const int* __restrict__ boff,
                     int* __restrict__ row_start, float* __restrict__ dinv,
                     float* __restrict__ rdinv, unsigned short* __restrict__ esrc,
                     const float* __restrict__ Wc3, const float* __restrict__ Acat,
                     _Float16* __restrict__ W3pk, _Float16* __restrict__ Apk) {
  int t = threadIdx.x;
  int b = blockIdx.x;
  if (b < NBLK) {  // ---- part2c ----
    __shared__ int cnt[256];
    __shared__ int cur[256];
    __shared__ int ss[256];
    int rs0 = boff[b], rs1 = boff[b + 1];
    cnt[t] = 0;
    __syncthreads();
    for (int i = rs0 + t; i < rs1; i += 256) {
      unsigned int p = epk2[i];
      atomicAdd(&cnt[(p >> 16) & 255], 1);
    }
    __syncthreads();
    int d = cnt[t];
    ss[t] = d;
    __syncthreads();
    for (int off = 1; off < 256; off <<= 1) {
      int v = (t >= off) ? ss[t - off] : 0;
      __syncthreads();
      ss[t] += v;
      __syncthreads();
    }
    int rs = rs0 + ss[t] - d;
    int node = b * 256 + t;
    if (node < NN) {
      row_start[node] = rs;
      float df = (float)d + 2.0f;
      dinv[node] = rsqrtf(df);
      rdinv[node] = sqrtf(df);
    }
    cur[t] = rs;
    __syncthreads();
    for (int i = rs0 + t; i < rs1; i += 256) {
      unsigned int p = epk2[i];
      int dl = (p >> 16) & 255;
      int tgt = atomicAdd(&cur[dl], 1);
      esrc[tgt] = (unsigned short)(p & 0xFFFFu);
    }
    return;
  }
  int id = (b - NBLK) * 256 + t;
  if (id < 1024) {
    int l = id & 63, nb = (id >> 6) & 7, kb = id >> 9;
    int kbase = kb * 32 + ((l >> 4) << 3);
    int col = nb * 16 + (l & 15);
#pragma unroll
    for (int j = 0; j < 8; ++j)
      W3pk[id * 8 + j] = (_Float16)Wc3[(kbase + j) * 128 + col];
  } else if (id < 1024 + 3584) {
    int idx = id - 1024;
    int l = idx & 63, nb = (idx >> 6) & 7, kb = idx >> 9;
    int kbase = kb * 32 + ((l >> 4) << 3);
    int col = nb * 16 + (l & 15);
#pragma unroll
    for (int j = 0; j < 8; ++j)
      Apk[idx * 8 + j] = (_Float16)Acat[(kbase + j) * 128 + col];
  }
}

// ---- convert 8 f32 -> half8 fragment ----
__device__ inline half8 cvt8f(const float* __restrict__ p) {
  float4 u = *reinterpret_cast<const float4*>(p);
  float4 v = *reinterpret_cast<const float4*>(p + 4);
  half8 a;
  a[0] = (_Float16)u.x; a[1] = (_Float16)u.y; a[2] = (_Float16)u.z; a[3] = (_Float16)u.w;
  a[4] = (_Float16)v.x; a[5] = (_Float16)v.y; a[6] = (_Float16)v.z; a[7] = (_Float16)v.w;
  return a;
}

// ---------------- layer-1 via MFMA: h1' = dinv[n] * (x @ w1) -> f16 ----------------
// 4 waves/block, 64 rows; per wave: 16-row strip, 2 N-frags; K=128 in 4 kb.
__launch_bounds__(256)
__global__ void k_gemm1m(const float* __restrict__ X, const half8* __restrict__ W1pk,
                         const float* __restrict__ dinv, _Float16* __restrict__ Yh) {
  int t = threadIdx.x;
  int w = t >> 6, l = t & 63;
  int m16 = l & 15, g = l >> 4;
  int n0 = blockIdx.x * 64 + w * 16;
  int nrow = n0 + m16;
  f32x4v acc[2];
  acc[0] = (f32x4v){0.f, 0.f, 0.f, 0.f};
  acc[1] = (f32x4v){0.f, 0.f, 0.f, 0.f};
#pragma unroll
  for (int kb = 0; kb < 4; ++kb) {
    half8 a = (half8)(_Float16)0.f;
    if (nrow < NN) a = cvt8f(X + (size_t)nrow * 128 + kb * 32 + g * 8);
#pragma unroll
    for (int nb = 0; nb < 2; ++nb)
      acc[nb] = __builtin_amdgcn_mfma_f32_16x16x32_f16(a, W1pk[(kb * 2 + nb) * 64 + l],
                                                       acc[nb], 0, 0, 0);
  }
#pragma unroll
  for (int nb = 0; nb < 2; ++nb)
#pragma unroll
    for (int r = 0; r < 4; ++r) {
      int n = n0 + g * 4 + r;
      if (n < NN)
        Yh[(size_t)n * 32 + nb * 16 + m16] = (_Float16)(dinv[n] * acc[nb][r]);
    }
}

// ---- coef-free 4-way gather sum, f16 rows F=32 ----
__device__ inline float4 gsum32h(const half4* __restrict__ H4,
                                 const unsigned short* __restrict__ esrc,
                                 const int* __restrict__ row_start,
                                 int n, int fg, int way) {
  float4 acc = make_float4(0.f, 0.f, 0.f, 0.f);
  if (way == 0) {
    half4 h = H4[(size_t)n * 8 + fg];
    acc.x = 2.f * (float)h[0]; acc.y = 2.f * (float)h[1];
    acc.z = 2.f * (float)h[2]; acc.w = 2.f * (float)h[3];
  }
  int end = row_start[n + 1];
  int i = row_start[n] + way;
  for (; i + 4 < end; i += 8) {
    int s0 = esrc[i], s1 = esrc[i + 4];
    half4 a = H4[(size_t)s0 * 8 + fg];
    half4 b = H4[(size_t)s1 * 8 + fg];
    acc.x += (float)a[0] + (float)b[0];
    acc.y += (float)a[1] + (float)b[1];
    acc.z += (float)a[2] + (float)b[2];
    acc.w += (float)a[3] + (float)b[3];
  }
  if (i < end) {
    int s = esrc[i];
    half4 a = H4[(size_t)s * 8 + fg];
    acc.x += (float)a[0]; acc.y += (float)a[1];
    acc.z += (float)a[2]; acc.w += (float)a[3];
  }
  acc.x += __shfl_xor(acc.x, 8);  acc.y += __shfl_xor(acc.y, 8);
  acc.z += __shfl_xor(acc.z, 8);  acc.w += __shfl_xor(acc.w, 8);
  acc.x += __shfl_xor(acc.x, 16); acc.y += __shfl_xor(acc.y, 16);
  acc.z += __shfl_xor(acc.z, 16); acc.w += __shfl_xor(acc.w, 16);
  return acc;
}

// ---- fuse1: gather(h1 f16) + GEMM 32->32 + relu -> x1 (f16, pre-scaled) ----
__launch_bounds__(256)
__global__ void k_fuse1(const _Float16* __restrict__ H, const unsigned short* __restrict__ esrc,
                        const int* __restrict__ row_start, const float* __restrict__ dinv,
                        const float* __restrict__ W, const float* __restrict__ bias,
                        _Float16* __restrict__ Y) {
  __shared__ float sZT[32][9];   // [feat][node], z = dinv*S
  __shared__ float sW[32 * 32];
  int t = threadIdx.x;
  int n0 = blockIdx.x * 8;
  {
    int kr = t >> 3, c4 = (t & 7) * 4;
    *reinterpret_cast<float4*>(&sW[kr * 32 + c4]) =
        *reinterpret_cast<const float4*>(&W[kr * 32 + c4]);
  }
  int node = t >> 5, fg = t & 7, way = (t >> 3) & 3;
  int n = n0 + node;
  float4 z = gsum32h(reinterpret_cast<const half4*>(H), esrc, row_start, n, fg, way);
  if (way == 0) {
    float dv = dinv[n];
    sZT[fg * 4 + 0][node] = dv * z.x;
    sZT[fg * 4 + 1][node] = dv * z.y;
    sZT[fg * 4 + 2][node] = dv * z.z;
    sZT[fg * 4 + 3][node] = dv * z.w;
  }
  __syncthreads();
  int nd = t >> 5, col = t & 31;
  float a = bias[col];
#pragma unroll
  for (int k = 0; k < 32; ++k) a = fmaf(sZT[k][nd], sW[k * 32 + col], a);
  Y[(size_t)(n0 + nd) * 32 + col] = (_Float16)(dinv[n0 + nd] * fmaxf(a, 0.f));
}

// ---- fuse2: gather(x1 f16) + GEMM 32->64 + relu -> x2 (f16, pre-scaled) ----
__launch_bounds__(256)
__global__ void k_fuse2(const _Float16* __restrict__ H, const unsigned short* __restrict__ esrc,
                        const int* __restrict__ row_start, const float* __restrict__ dinv,
                        const float* __restrict__ W, const float* __restrict__ bias,
                        _Float16* __restrict__ Y) {
  __shared__ float sZT[32][9];
  __shared__ float sW[32 * 64];
  int t = threadIdx.x;
  int n0 = blockIdx.x * 8;
#pragma unroll
  for (int it = 0; it < 2; ++it) {
    int idx = t + it * 256;
    int kr = idx >> 4, c4 = (idx & 15) * 4;
    *reinterpret_cast<float4*>(&sW[kr * 64 + c4]) =
        *reinterpret_cast<const float4*>(&W[kr * 64 + c4]);
  }
  int node = t >> 5, fg = t & 7, way = (t >> 3) & 3;
  int n = n0 + node;
  float4 z = gsum32h(reinterpret_cast<const half4*>(H), esrc, row_start, n, fg, way);
  if (way == 0) {
    float dv = dinv[n];
    sZT[fg * 4 + 0][node] = dv * z.x;
    sZT[fg * 4 + 1][node] = dv * z.y;
    sZT[fg * 4 + 2][node] = dv * z.z;
    sZT[fg * 4 + 3][node] = dv * z.w;
  }
  __syncthreads();
  int nd = t >> 5, col = t & 31;
  float a = bias[col], b = bias[col + 32];
#pragma unroll
  for (int k = 0; k < 32; ++k) {
    float zv = sZT[k][nd];
    a = fmaf(zv, sW[k * 64 + col], a);
    b = fmaf(zv, sW[k * 64 + col + 32], b);
  }
  float dv = dinv[n0 + nd];
  Y[(size_t)(n0 + nd) * 64 + col] = (_Float16)(dv * fmaxf(a, 0.f));
  Y[(size_t)(n0 + nd) * 64 + col + 32] = (_Float16)(dv * fmaxf(b, 0.f));
}

// ------- gath64: gather(x2 f16, 128 B/row) -> z3 (true scale) as f16 -------
__launch_bounds__(256)
__global__ void k_gath64(const _Float16* __restrict__ H, const unsigned short* __restrict__ esrc,
                         const int* __restrict__ row_start, const float* __restrict__ dinv,
                         _Float16* __restrict__ Zh) {
  int t = threadIdx.x;
  int n = blockIdx.x * 4 + (t >> 6);
  int fg = t & 15, way = (t >> 4) & 3;
  const half4* H4 = reinterpret_cast<const half4*>(H);
  float4 acc = make_float4(0.f, 0.f, 0.f, 0.f);
  if (way == 0) {
    half4 h = H4[(size_t)n * 16 + fg];
    acc.x = 2.f * (float)h[0]; acc.y = 2.f * (float)h[1];
    acc.z = 2.f * (float)h[2]; acc.w = 2.f * (float)h[3];
  }
  int end = row_start[n + 1];
  int i = row_start[n] + way;
  for (; i + 4 < end; i += 8) {
    int s0 = esrc[i], s1 = esrc[i + 4];
    half4 a = H4[(size_t)s0 * 16 + fg];
    half4 b = H4[(size_t)s1 * 16 + fg];
    acc.x += (float)a[0] + (float)b[0];
    acc.y += (float)a[1] + (float)b[1];
    acc.z += (float)a[2] + (float)b[2];
    acc.w += (float)a[3] + (float)b[3];
  }
  if (i < end) {
    int s = esrc[i];
    half4 a = H4[(size_t)s * 16 + fg];
    acc.x += (float)a[0]; acc.y += (float)a[1];
    acc.z += (float)a[2]; acc.w += (float)a[3];
  }
  acc.x += __shfl_xor(acc.x, 16); acc.y += __shfl_xor(acc.y, 16);
  acc.z += __shfl_xor(acc.z, 16); acc.w += __shfl_xor(acc.w, 16);
  acc.x += __shfl_xor(acc.x, 32); acc.y += __shfl_xor(acc.y, 32);
  acc.z += __shfl_xor(acc.z, 32); acc.w += __shfl_xor(acc.w, 32);
  if (way == 0) {
    float dv = dinv[n];
    half4 hv;
    hv[0] = (_Float16)(dv * acc.x); hv[1] = (_Float16)(dv * acc.y);
    hv[2] = (_Float16)(dv * acc.z); hv[3] = (_Float16)(dv * acc.w);
    *reinterpret_cast<half4*>(Zh + (size_t)n * 64 + fg * 4) = hv;
  }
}

// ---- read half8, unscale by s, repack ----
__device__ inline half8 cvt8h(const _Float16* __restrict__ p, float s) {
  half8 v = *reinterpret_cast<const half8*>(p);
  half8 a;
#pragma unroll
  for (int i = 0; i < 8; ++i) a[i] = (_Float16)(s * (float)v[i]);
  return a;
}

// ------- MFMA decode: x3 = relu(z3@Wc3+bc3); out = c0 + [x3|x2|x1] @ Acat -------
__launch_bounds__(256)
__global__ void k_decode(const _Float16* __restrict__ z3h, const _Float16* __restrict__ X2h,
                         const _Float16* __restrict__ X1h, const float* __restrict__ rdinv,
                         const half8* __restrict__ W3pk, const half8* __restrict__ Apk,
                         const float* __restrict__ bc3, const float* __restrict__ c0,
                         float* __restrict__ out) {
  __shared__ _Float16 sX3[4][16][136];
  int t = threadIdx.x;
  int w = t >> 6, l = t & 63;
  int m16 = l & 15, g = l >> 4;
  int n0 = blockIdx.x * 64 + w * 16;
  int nrow = n0 + m16;

  f32x4v acc[8];
  // ---- Phase B: x3 = relu(z3 @ Wc3 + bc3), K=64 ----
#pragma unroll
  for (int nb = 0; nb < 8; ++nb) {
    float bv = bc3[nb * 16 + m16];
    acc[nb] = (f32x4v){bv, bv, bv, bv};
  }
#pragma unroll
  for (int kb = 0; kb < 2; ++kb) {
    half8 a = *reinterpret_cast<const half8*>(z3h + (size_t)nrow * 64 + kb * 32 + g * 8);
#pragma unroll
    for (int nb = 0; nb < 8; ++nb) {
      half8 b = W3pk[(kb * 8 + nb) * 64 + l];
      acc[nb] = __builtin_amdgcn_mfma_f32_16x16x32_f16(a, b, acc[nb], 0, 0, 0);
    }
  }
#pragma unroll
  for (int nb = 0; nb < 8; ++nb)
#pragma unroll
    for (int r = 0; r < 4; ++r)
      sX3[w][g * 4 + r][nb * 16 + m16] = (_Float16)fmaxf(acc[nb][r], 0.0f);
  __syncthreads();

  // ---- Phase C: out = c0 + [x3|x2|x1] @ Acat, K=224 ----
  float rd = rdinv[nrow];
#pragma unroll
  for (int nb = 0; nb < 8; ++nb) {
    float cv = c0[nb * 16 + m16];
    acc[nb] = (f32x4v){cv, cv, cv, cv};
  }
#pragma unroll
  for (int kb = 0; kb < 7; ++kb) {
    half8 a;
    if (kb < 4)
      a = *reinterpret_cast<const half8*>(&sX3[w][m16][kb * 32 + g * 8]);
    else if (kb < 6)
      a = cvt8h(X2h + (size_t)nrow * 64 + (kb - 4) * 32 + g * 8, rd);
    else
      a = cvt8h(X1h + (size_t)nrow * 32 + g * 8, rd);
#pragma unroll
    for (int nb = 0; nb < 8; ++nb) {
      half8 b = Apk[(kb * 8 + nb) * 64 + l];
      acc[nb] = __builtin_amdgcn_mfma_f32_16x16x32_f16(a, b, acc[nb], 0, 0, 0);
    }
  }
#pragma unroll
  for (int nb = 0; nb < 8; ++nb)
#pragma unroll
    for (int r = 0; r < 4; ++r) {
      int n = n0 + g * 4 + r;
      if (n < NN) out[(size_t)n * 128 + nb * 16 + m16] = acc[nb][r];
    }
}

extern "C" void kernel_launch(void* const* d_in, const int* in_sizes, int n_in,
                              void* d_out, int out_size, void* d_ws, size_t ws_size,
                              hipStream_t stream) {
  const float* x   = (const float*)d_in[0];
  const int* ei    = (const int*)d_in[1];
  const int* srcv  = ei;
  const int* dstv  = ei + NE;
  const float* w1  = (const float*)d_in[2];
  const float* b1  = (const float*)d_in[3];
  const float* fw1 = (const float*)d_in[4];
  const float* fb1 = (const float*)d_in[5];
  const float* w2  = (const float*)d_in[6];
  const float* b2  = (const float*)d_in[7];
  const float* fw2 = (const float*)d_in[8];
  const float* fb2 = (const float*)d_in[9];
  const float* w3  = (const float*)d_in[10];
  const float* b3  = (const float*)d_in[11];
  const float* fw3 = (const float*)d_in[12];
  const float* fb3 = (const float*)d_in[13];
  const float* wd1 = (const float*)d_in[14];
  const float* bd1 = (const float*)d_in[15];
  const float* wd2 = (const float*)d_in[16];
  const float* bd2 = (const float*)d_in[17];
  const float* wd3 = (const float*)d_in[18];
  const float* bd3 = (const float*)d_in[19];
  const float* ws1 = (const float*)d_in[20];
  const float* bs1 = (const float*)d_in[21];
  const float* ws2 = (const float*)d_in[22];
  const float* bs2 = (const float*)d_in[23];
  const float* wf  = (const float*)d_in[24];
  const float* bf  = (const float*)d_in[25];

  float* fp = (float*)d_ws;
  float* dinv = fp;                         // 50176
  float* rdinv= dinv + 50176;               // 50176
  _Float16* h1h = (_Float16*)(rdinv + 50176);  // 50048*32 halves
  _Float16* x1h = h1h + 1601536;               // 50048*32 halves
  _Float16* x2h = x1h + 1601536;               // 50048*64 halves
  _Float16* z3h = x2h + 3203072;               // 50048*64 halves
  float* Wc2  = (float*)(z3h + 3203072);    // 2048
  float* Wc3  = Wc2 + 2048;                 // 8192
  float* bc1  = Wc3 + 8192;                 // 64
  float* bc2  = bc1 + 64;                   // 64
  float* bc3  = bc2 + 64;                   // 128
  float* G    = bc3 + 128;                  // 16384
  float* Hm   = G + 16384;                  // 16384
  float* A3   = Hm + 16384;                 // 16384 } Acat = A3|A2|A1 [224][128]
  float* A2   = A3 + 16384;                 // 8192  }
  float* A1   = A2 + 8192;                  // 4096  }
  float* c0   = A1 + 4096;                  // 256
  _Float16* W3pk = (_Float16*)(c0 + 256);   // 8192 halves
  _Float16* Apk  = W3pk + 8192;             // 28672 halves
  _Float16* W1pk = Apk + 28672;             // 4096 halves
  unsigned int* epk2 = (unsigned int*)(W1pk + 4096);       // 800000 u32
  unsigned short* esrc = (unsigned short*)(epk2 + 800000); // 800000 u16
  int* ip     = (int*)(esrc + 800128);      // (pad to 4B align)
  int* row_start = ip;                      // 50176 (NN+1 used)
  int* bcnt2  = row_start + 50176;          // 196*256 = 50176
  int* boff   = bcnt2 + 50176;              // 197(+pad)
  int* bcur   = boff + 260;                 // 256

  float* outp = (float*)d_out;

  // ---- K1: bucket-count + prep1 + w1 pack ----
  k_u1<<<NBLK + 105 + 1, 256, 0, stream>>>(dstv, bcnt2,
                                           wd3, wf, w2, fw2, w3, fw3, b1, fw1, fb1,
                                           b2, fb2, b3, fb3, G, Wc2, Wc3, bc1, bc2, bc3,
                                           w1, W1pk);
  // ---- K2: bucket scan + prep_HA1 ----
  k_u2<<<1 + 80, 256, 0, stream>>>(bcnt2, boff, bcur, row_start, wd2, G, ws2, Hm, A1);
  // ---- K3: part1 + prep_A32c0 ----
  k_u3<<<NBLK + 97, 256, 0, stream>>>(srcv, dstv, bcur, epk2,
                                      wd1, ws1, Hm, G, wf, bd1, bs1, bd2, bs2, bd3, bf,
                                      A3, A2, c0);
  // ---- K4: part2c + B-fragment pack ----
  k_u4<<<NBLK + 18, 256, 0, stream>>>(epk2, boff, row_start, dinv, rdinv, esrc,
                                      Wc3, A3 /*Acat*/, W3pk, Apk);

  // ---- pipeline ----
  k_gemm1m<<<(NN + 63) / 64, 256, 0, stream>>>(x, (const half8*)W1pk, dinv, h1h);
  k_fuse1<<<NN / 8, 256, 0, stream>>>(h1h, esrc, row_start, dinv, fw1, bc1, x1h);
  k_fuse2<<<NN / 8, 256, 0, stream>>>(x1h, esrc, row_start, dinv, Wc2, bc2, x2h);
  k_gath64<<<NN / 4, 256, 0, stream>>>(x2h, esrc, row_start, dinv, z3h);
  k_decode<<<(NN + 63) / 64, 256, 0, stream>>>(z3h, x2h, x1h, rdinv, (const half8*)W3pk,
                                               (const half8*)Apk, bc3, c0, outp);
}

// Round 12
// 139.676 us; speedup vs baseline: 1.7061x; 1.0536x over previous
//
#include <hip/hip_runtime.h>

#define NN 50000
#define NE 800000
#define NBLK 196   // bucket count (256 nodes/bucket); also edge-chunk blocks
#define CAP 5120   // padded slots per bucket (mean 4082, +16 sigma)

typedef _Float16 half8 __attribute__((ext_vector_type(8)));
typedef _Float16 half4 __attribute__((ext_vector_type(4)));
typedef float f32x4v __attribute__((ext_vector_type(4)));

// =================== K_A: padded partition pass 1 + prep1 + w1 pack ===================
__launch_bounds__(256)
__global__ void k_A(const int* __restrict__ srcv, const int* __restrict__ dstv,
                    int* __restrict__ bcur, unsigned int* __restrict__ epk2,
                    const float* __restrict__ wd3, const float* __restrict__ wf,
                    const float* __restrict__ w2, const float* __restrict__ fw2,
                    const float* __restrict__ w3, const float* __restrict__ fw3,
                    const float* __restrict__ b1, const float* __restrict__ fw1,
                    const float* __restrict__ fb1,
                    const float* __restrict__ b2, const float* __restrict__ fb2,
                    const float* __restrict__ b3, const float* __restrict__ fb3,
                    float* __restrict__ G,
                    float* __restrict__ Wc2, float* __restrict__ Wc3,
                    float* __restrict__ bc1, float* __restrict__ bc2,
                    float* __restrict__ bc3,
                    const float* __restrict__ w1, _Float16* __restrict__ W1pk) {
  __shared__ int cnt[256];
  __shared__ int base[256];
  int t = threadIdx.x;
  int b = blockIdx.x;
  if (b < NBLK) {  // ---- part1 (padded buckets, no prior histogram) ----
    int e0 = b * 4096;
    cnt[t] = 0;
    __syncthreads();
    unsigned int pk[16];
    int lo[16], bk[16];
    bool ok[16];
#pragma unroll
    for (int i = 0; i < 16; ++i) {
      int e = e0 + i * 256 + t;
      ok[i] = (e < NE);
      if (ok[i]) {
        int s = srcv[e], d = dstv[e];
        bk[i] = d >> 8;
        pk[i] = (unsigned int)s | ((unsigned int)(d & 255) << 16);
        lo[i] = atomicAdd(&cnt[bk[i]], 1);
      }
    }
    __syncthreads();
    int c = cnt[t];
    if (c > 0) base[t] = atomicAdd(&bcur[t], c);
    __syncthreads();
#pragma unroll
    for (int i = 0; i < 16; ++i)
      if (ok[i]) epk2[(size_t)bk[i] * CAP + base[bk[i]] + lo[i]] = pk[i];
    return;
  }
  if (b < NBLK + 105) {  // ---- prep1: G + Wc2/Wc3/bc1/bc2/bc3 ----
    int id = (b - NBLK) * 256 + t;
    if (id < 16384) {                      // G[c*4+l, k]
      int k = id & 127, r = id >> 7;
      int c = r >> 2, l = r & 3;
      float s = 0.f;
      for (int o = 0; o < 32; ++o) {
        s = fmaf(wd3[c * 64 + o * 2 + 0], wf[(o * 8 + 2 * l + 0) * 128 + k], s);
        s = fmaf(wd3[c * 64 + o * 2 + 1], wf[(o * 8 + 2 * l + 1) * 128 + k], s);
      }
      G[r * 128 + k] = s;
      return;
    }
    int id2 = id - 16384;
    if (id2 < 2048) {                      // Wc2 [32,64]
      int c = id2 >> 6, k = id2 & 63;
      float s = 0.f;
      for (int j = 0; j < 64; ++j) s = fmaf(w2[c * 64 + j], fw2[j * 64 + k], s);
      Wc2[id2] = s;
    } else if (id2 < 10240) {              // Wc3 [64,128]
      int idx = id2 - 2048;
      int c = idx >> 7, k = idx & 127;
      float s = 0.f;
      for (int j = 0; j < 128; ++j) s = fmaf(w3[c * 128 + j], fw3[j * 128 + k], s);
      Wc3[idx] = s;
    } else if (id2 < 10272) {              // bc1 [32]
      int k = id2 - 10240;
      float s = fb1[k];
      for (int j = 0; j < 32; ++j) s = fmaf(b1[j], fw1[j * 32 + k], s);
      bc1[k] = s;
    } else if (id2 < 10336) {              // bc2 [64]
      int k = id2 - 10272;
      float s = fb2[k];
      for (int j = 0; j < 64; ++j) s = fmaf(b2[j], fw2[j * 64 + k], s);
      bc2[k] = s;
    } else if (id2 < 10464) {              // bc3 [128]
      int k = id2 - 10336;
      float s = fb3[k];
      for (int j = 0; j < 128; ++j) s = fmaf(b3[j], fw3[j * 128 + k], s);
      bc3[k] = s;
    }
    return;
  }
  // ---- pack w1 [128][32] fragments: frag (kb,nb) kb<4, nb<2 ----
#pragma unroll
  for (int it = 0; it < 2; ++it) {
    int id = t + it * 256;
    int l = id & 63, f = id >> 6;
    int kb = f >> 1, nb = f & 1;
    int kbase = kb * 32 + ((l >> 4) << 3);
    int col = nb * 16 + (l & 15);
#pragma unroll
    for (int j = 0; j < 8; ++j)
      W1pk[id * 8 + j] = (_Float16)w1[(kbase + j) * 32 + col];
  }
}

// ====== K_B: pass 2 (per-node degree + local scan + place, padded) + prep_HA1 ======
__launch_bounds__(256)
__global__ void k_B(const unsigned int* __restrict__ epk2, const int* __restrict__ bcur,
                    int* __restrict__ row_start, int* __restrict__ bend,
                    float* __restrict__ dinv, float* __restrict__ rdinv,
                    unsigned short* __restrict__ esrc,
                    const float* __restrict__ wd2, const float* __restrict__ G,
                    const float* __restrict__ ws2,
                    float* __restrict__ Hm, float* __restrict__ A1) {
  int t = threadIdx.x;
  int b = blockIdx.x;
  if (b < NBLK) {  // ---- part2 ----
    __shared__ int cnt[256];
    __shared__ int cur[256];
    __shared__ int ss[256];
    int rs0 = b * CAP;
    int count = bcur[b];
    int rs1 = rs0 + count;
    cnt[t] = 0;
    __syncthreads();
    for (int i = rs0 + t; i < rs1; i += 256) {
      unsigned int p = epk2[i];
      atomicAdd(&cnt[(p >> 16) & 255], 1);
    }
    __syncthreads();
    int d = cnt[t];
    ss[t] = d;
    __syncthreads();
    for (int off = 1; off < 256; off <<= 1) {
      int v = (t >= off) ? ss[t - off] : 0;
      __syncthreads();
      ss[t] += v;
      __syncthreads();
    }
    int rs = rs0 + ss[t] - d;
    int node = b * 256 + t;
    if (node < NN) {
      row_start[node] = rs;
      float df = (float)d + 2.0f;
      dinv[node] = rsqrtf(df);
      rdinv[node] = sqrtf(df);
    }
    if (t == 0) bend[b] = rs1;
    if (b == 0 && t == 0) row_start[NN] = NBLK * CAP;
    cur[t] = rs;
    __syncthreads();
    for (int i = rs0 + t; i < rs1; i += 256) {
      unsigned int p = epk2[i];
      int dl = (p >> 16) & 255;
      int tgt = atomicAdd(&cur[dl], 1);
      esrc[tgt] = (unsigned short)(p & 0xFFFFu);
    }
    return;
  }
  int id = (b - NBLK) * 256 + t;
  if (id < 16384) {
    int k = id & 127, r = id >> 7;
    int c = r >> 1, l = r & 1;
    float s = 0.f;
    for (int o = 0; o < 32; ++o) {
      s = fmaf(wd2[c * 64 + o * 2 + 0], G[(o * 4 + 2 * l + 0) * 128 + k], s);
      s = fmaf(wd2[c * 64 + o * 2 + 1], G[(o * 4 + 2 * l + 1) * 128 + k], s);
    }
    Hm[r * 128 + k] = s;
  } else if (id < 16384 + 4096) {
    int idx = id - 16384;
    int k = idx & 127, c = idx >> 7;   // c < 32
    float s = 0.f;
    for (int o = 0; o < 32; ++o) {
      float g = G[(4 * o) * 128 + k] + G[(4 * o + 1) * 128 + k] +
                G[(4 * o + 2) * 128 + k] + G[(4 * o + 3) * 128 + k];
      s = fmaf(ws2[c * 32 + o], g, s);
    }
    A1[c * 128 + k] = s;
  }
}

// ---- convert 8 f32 -> half8 fragment ----
__device__ inline half8 cvt8f(const float* __restrict__ p) {
  float4 u = *reinterpret_cast<const float4*>(p);
  float4 v = *reinterpret_cast<const float4*>(p + 4);
  half8 a;
  a[0] = (_Float16)u.x; a[1] = (_Float16)u.y; a[2] = (_Float16)u.z; a[3] = (_Float16)u.w;
  a[4] = (_Float16)v.x; a[5] = (_Float16)v.y; a[6] = (_Float16)v.z; a[7] = (_Float16)v.w;
  return a;
}

// ============ K_C: layer-1 MFMA (h1' = dinv*(x@w1) -> f16) + prep_A32c0 ============
#define NG1 782  // (NN+63)/64
__launch_bounds__(256)
__global__ void k_C(const float* __restrict__ X, const half8* __restrict__ W1pk,
                    const float* __restrict__ dinv, _Float16* __restrict__ Yh,
                    const float* __restrict__ wd1, const float* __restrict__ ws1,
                    const float* __restrict__ Hm, const float* __restrict__ G,
                    const float* __restrict__ wf,
                    const float* __restrict__ bd1, const float* __restrict__ bs1,
                    const float* __restrict__ bd2, const float* __restrict__ bs2,
                    const float* __restrict__ bd3, const float* __restrict__ bf,
                    float* __restrict__ A3, float* __restrict__ A2,
                    float* __restrict__ c0) {
  int t = threadIdx.x;
  int b = blockIdx.x;
  if (b < NG1) {  // ---- gemm1m ----
    int w = t >> 6, l = t & 63;
    int m16 = l & 15, g = l >> 4;
    int n0 = b * 64 + w * 16;
    int nrow = n0 + m16;
    f32x4v acc[2];
    acc[0] = (f32x4v){0.f, 0.f, 0.f, 0.f};
    acc[1] = (f32x4v){0.f, 0.f, 0.f, 0.f};
#pragma unroll
    for (int kb = 0; kb < 4; ++kb) {
      half8 a = (half8)(_Float16)0.f;
      if (nrow < NN) a = cvt8f(X + (size_t)nrow * 128 + kb * 32 + g * 8);
#pragma unroll
      for (int nb = 0; nb < 2; ++nb)
        acc[nb] = __builtin_amdgcn_mfma_f32_16x16x32_f16(a, W1pk[(kb * 2 + nb) * 64 + l],
                                                         acc[nb], 0, 0, 0);
    }
#pragma unroll
    for (int nb = 0; nb < 2; ++nb)
#pragma unroll
      for (int r = 0; r < 4; ++r) {
        int n = n0 + g * 4 + r;
        if (n < NN)
          Yh[(size_t)n * 32 + nb * 16 + m16] = (_Float16)(dinv[n] * acc[nb][r]);
      }
    return;
  }
  int id = (b - NG1) * 256 + t;
  if (id < 16384) {
    int k = id & 127, c = id >> 7;
    float s = 0.f;
    for (int j = 0; j < 128; ++j) s = fmaf(wd1[c * 128 + j], Hm[j * 128 + k], s);
    A3[c * 128 + k] = s;
  } else if (id < 16384 + 8192) {
    int idx = id - 16384;
    int k = idx & 127, c = idx >> 7;   // c < 64
    float s = 0.f;
    for (int o = 0; o < 64; ++o)
      s = fmaf(ws1[c * 64 + o], Hm[(2 * o) * 128 + k] + Hm[(2 * o + 1) * 128 + k], s);
    A2[c * 128 + k] = s;
  } else if (id < 16384 + 8192 + 128) {
    int k = id - 16384 - 8192;
    float s = bf[k];
    for (int o = 0; o < 64; ++o) {
      float bb = bd1[o] + bs1[o];
      s = fmaf(bb, Hm[(o * 2) * 128 + k] + Hm[(o * 2 + 1) * 128 + k], s);
    }
    for (int o = 0; o < 32; ++o) {
      float bb = bd2[o] + bs2[o];
      float g = G[(o * 4) * 128 + k] + G[(o * 4 + 1) * 128 + k] +
                G[(o * 4 + 2) * 128 + k] + G[(o * 4 + 3) * 128 + k];
      s = fmaf(bb, g, s);
    }
    for (int o = 0; o < 32; ++o) {
      float w8 = 0.f;
      for (int j = 0; j < 8; ++j) w8 += wf[(o * 8 + j) * 128 + k];
      s = fmaf(bd3[o], w8, s);
    }
    c0[k] = s;
  }
}

// ---- coef-free 4-way gather sum, f16 rows F=32; 4 edges in flight ----
__device__ inline float4 gsum32h(const half4* __restrict__ H4,
                                 const unsigned short* __restrict__ esrc,
                                 const int* __restrict__ row_start,
                                 const int* __restrict__ bend,
                                 int n, int fg, int way) {
  float4 acc = make_float4(0.f, 0.f, 0.f, 0.f);
  if (way == 0) {
    half4 h = H4[(size_t)n * 8 + fg];
    acc.x = 2.f * (float)h[0]; acc.y = 2.f * (float)h[1];
    acc.z = 2.f * (float)h[2]; acc.w = 2.f * (float)h[3];
  }
  int end = min(row_start[n + 1], bend[n >> 8]);
  int i = row_start[n] + way;
  for (; i + 12 < end; i += 16) {
    int s0 = esrc[i], s1 = esrc[i + 4], s2 = esrc[i + 8], s3 = esrc[i + 12];
    half4 a = H4[(size_t)s0 * 8 + fg];
    half4 b = H4[(size_t)s1 * 8 + fg];
    half4 c = H4[(size_t)s2 * 8 + fg];
    half4 d = H4[(size_t)s3 * 8 + fg];
    acc.x += ((float)a[0] + (float)b[0]) + ((float)c[0] + (float)d[0]);
    acc.y += ((float)a[1] + (float)b[1]) + ((float)c[1] + (float)d[1]);
    acc.z += ((float)a[2] + (float)b[2]) + ((float)c[2] + (float)d[2]);
    acc.w += ((float)a[3] + (float)b[3]) + ((float)c[3] + (float)d[3]);
  }
  for (; i < end; i += 4) {
    int s = esrc[i];
    half4 a = H4[(size_t)s * 8 + fg];
    acc.x += (float)a[0]; acc.y += (float)a[1];
    acc.z += (float)a[2]; acc.w += (float)a[3];
  }
  acc.x += __shfl_xor(acc.x, 8);  acc.y += __shfl_xor(acc.y, 8);
  acc.z += __shfl_xor(acc.z, 8);  acc.w += __shfl_xor(acc.w, 8);
  acc.x += __shfl_xor(acc.x, 16); acc.y += __shfl_xor(acc.y, 16);
  acc.z += __shfl_xor(acc.z, 16); acc.w += __shfl_xor(acc.w, 16);
  return acc;
}

// ====== K_D: fuse1 (gather h1 + GEMM 32->32 + relu -> x1 f16) + B-frag pack ======
#define NF1 6250  // NN/8
__launch_bounds__(256)
__global__ void k_D(const _Float16* __restrict__ H, const unsigned short* __restrict__ esrc,
                    const int* __restrict__ row_start, const int* __restrict__ bend,
                    const float* __restrict__ dinv,
                    const float* __restrict__ W, const float* __restrict__ bias,
                    _Float16* __restrict__ Y,
                    const float* __restrict__ Wc3, const float* __restrict__ Acat,
                    _Float16* __restrict__ W3pk, _Float16* __restrict__ Apk) {
  int t = threadIdx.x;
  int b = blockIdx.x;
  if (b < NF1) {  // ---- fuse1 ----
    __shared__ float sZT[32][9];
    __shared__ float sW[32 * 32];
    int n0 = b * 8;
    {
      int kr = t >> 3, c4 = (t & 7) * 4;
      *reinterpret_cast<float4*>(&sW[kr * 32 + c4]) =
          *reinterpret_cast<const float4*>(&W[kr * 32 + c4]);
    }
    int node = t >> 5, fg = t & 7, way = (t >> 3) & 3;
    int n = n0 + node;
    float4 z = gsum32h(reinterpret_cast<const half4*>(H), esrc, row_start, bend, n, fg, way);
    if (way == 0) {
      float dv = dinv[n];
      sZT[fg * 4 + 0][node] = dv * z.x;
      sZT[fg * 4 + 1][node] = dv * z.y;
      sZT[fg * 4 + 2][node] = dv * z.z;
      sZT[fg * 4 + 3][node] = dv * z.w;
    }
    __syncthreads();
    int nd = t >> 5, col = t & 31;
    float a = bias[col];
#pragma unroll
    for (int k = 0; k < 32; ++k) a = fmaf(sZT[k][nd], sW[k * 32 + col], a);
    Y[(size_t)(n0 + nd) * 32 + col] = (_Float16)(dinv[n0 + nd] * fmaxf(a, 0.f));
    return;
  }
  int id = (b - NF1) * 256 + t;
  if (id < 1024) {
    int l = id & 63, nb = (id >> 6) & 7, kb = id >> 9;
    int kbase = kb * 32 + ((l >> 4) << 3);
    int col = nb * 16 + (l & 15);
#pragma unroll
    for (int j = 0; j < 8; ++j)
      W3pk[id * 8 + j] = (_Float16)Wc3[(kbase + j) * 128 + col];
  } else if (id < 1024 + 3584) {
    int idx = id - 1024;
    int l = idx & 63, nb = (idx >> 6) & 7, kb = idx >> 9;
    int kbase = kb * 32 + ((l >> 4) << 3);
    int col = nb * 16 + (l & 15);
#pragma unroll
    for (int j = 0; j < 8; ++j)
      Apk[idx * 8 + j] = (_Float16)Acat[(kbase + j) * 128 + col];
  }
}

// ---- fuse2: gather(x1 f16) + GEMM 32->64 + relu -> x2 (f16, pre-scaled) ----
__launch_bounds__(256)
__global__ void k_fuse2(const _Float16* __restrict__ H, const unsigned short* __restrict__ esrc,
                        const int* __restrict__ row_start, const int* __restrict__ bend,
                        const float* __restrict__ dinv,
                        const float* __restrict__ W, const float* __restrict__ bias,
                        _Float16* __restrict__ Y) {
  __shared__ float sZT[32][9];
  __shared__ float sW[32 * 64];
  int t = threadIdx.x;
  int n0 = blockIdx.x * 8;
#pragma unroll
  for (int it = 0; it < 2; ++it) {
    int idx = t + it * 256;
    int kr = idx >> 4, c4 = (idx & 15) * 4;
    *reinterpret_cast<float4*>(&sW[kr * 64 + c4]) =
        *reinterpret_cast<const float4*>(&W[kr * 64 + c4]);
  }
  int node = t >> 5, fg = t & 7, way = (t >> 3) & 3;
  int n = n0 + node;
  float4 z = gsum32h(reinterpret_cast<const half4*>(H), esrc, row_start, bend, n, fg, way);
  if (way == 0) {
    float dv = dinv[n];
    sZT[fg * 4 + 0][node] = dv * z.x;
    sZT[fg * 4 + 1][node] = dv * z.y;
    sZT[fg * 4 + 2][node] = dv * z.z;
    sZT[fg * 4 + 3][node] = dv * z.w;
  }
  __syncthreads();
  int nd = t >> 5, col = t & 31;
  float a = bias[col], b = bias[col + 32];
#pragma unroll
  for (int k = 0; k < 32; ++k) {
    float zv = sZT[k][nd];
    a = fmaf(zv, sW[k * 64 + col], a);
    b = fmaf(zv, sW[k * 64 + col + 32], b);
  }
  float dv = dinv[n0 + nd];
  Y[(size_t)(n0 + nd) * 64 + col] = (_Float16)(dv * fmaxf(a, 0.f));
  Y[(size_t)(n0 + nd) * 64 + col + 32] = (_Float16)(dv * fmaxf(b, 0.f));
}

// ------- gath64: gather(x2 f16, 128 B/row) -> z3 (true scale) as f16 -------
__launch_bounds__(256)
__global__ void k_gath64(const _Float16* __restrict__ H, const unsigned short* __restrict__ esrc,
                         const int* __restrict__ row_start, const int* __restrict__ bend,
                         const float* __restrict__ dinv, _Float16* __restrict__ Zh) {
  int t = threadIdx.x;
  int n = blockIdx.x * 4 + (t >> 6);
  int fg = t & 15, way = (t >> 4) & 3;
  const half4* H4 = reinterpret_cast<const half4*>(H);
  float4 acc = make_float4(0.f, 0.f, 0.f, 0.f);
  if (way == 0) {
    half4 h = H4[(size_t)n * 16 + fg];
    acc.x = 2.f * (float)h[0]; acc.y = 2.f * (float)h[1];
    acc.z = 2.f * (float)h[2]; acc.w = 2.f * (float)h[3];
  }
  int end = min(row_start[n + 1], bend[n >> 8]);
  int i = row_start[n] + way;
  for (; i + 12 < end; i += 16) {
    int s0 = esrc[i], s1 = esrc[i + 4], s2 = esrc[i + 8], s3 = esrc[i + 12];
    half4 a = H4[(size_t)s0 * 16 + fg];
    half4 b = H4[(size_t)s1 * 16 + fg];
    half4 c = H4[(size_t)s2 * 16 + fg];
    half4 d = H4[(size_t)s3 * 16 + fg];
    acc.x += ((float)a[0] + (float)b[0]) + ((float)c[0] + (float)d[0]);
    acc.y += ((float)a[1] + (float)b[1]) + ((float)c[1] + (float)d[1]);
    acc.z += ((float)a[2] + (float)b[2]) + ((float)c[2] + (float)d[2]);
    acc.w += ((float)a[3] + (float)b[3]) + ((float)c[3] + (float)d[3]);
  }
  for (; i < end; i += 4) {
    int s = esrc[i];
    half4 a = H4[(size_t)s * 16 + fg];
    acc.x += (float)a[0]; acc.y += (float)a[1];
    acc.z += (float)a[2]; acc.w += (float)a[3];
  }
  acc.x += __shfl_xor(acc.x, 16); acc.y += __shfl_xor(acc.y, 16);
  acc.z += __shfl_xor(acc.z, 16); acc.w += __shfl_xor(acc.w, 16);
  acc.x += __shfl_xor(acc.x, 32); acc.y += __shfl_xor(acc.y, 32);
  acc.z += __shfl_xor(acc.z, 32); acc.w += __shfl_xor(acc.w, 32);
  if (way == 0) {
    float dv = dinv[n];
    half4 hv;
    hv[0] = (_Float16)(dv * acc.x); hv[1] = (_Float16)(dv * acc.y);
    hv[2] = (_Float16)(dv * acc.z); hv[3] = (_Float16)(dv * acc.w);
    *reinterpret_cast<half4*>(Zh + (size_t)n * 64 + fg * 4) = hv;
  }
}

// ---- read half8, unscale by s, repack ----
__device__ inline half8 cvt8h(const _Float16* __restrict__ p, float s) {
  half8 v = *reinterpret_cast<const half8*>(p);
  half8 a;
#pragma unroll
  for (int i = 0; i < 8; ++i) a[i] = (_Float16)(s * (float)v[i]);
  return a;
}

// ------- MFMA decode: x3 = relu(z3@Wc3+bc3); out = c0 + [x3|x2|x1] @ Acat -------
__launch_bounds__(256)
__global__ void k_decode(const _Float16* __restrict__ z3h, const _Float16* __restrict__ X2h,
                         const _Float16* __restrict__ X1h, const float* __restrict__ rdinv,
                         const half8* __restrict__ W3pk, const half8* __restrict__ Apk,
                         const float* __restrict__ bc3, const float* __restrict__ c0,
                         float* __restrict__ out) {
  __shared__ _Float16 sX3[4][16][136];
  int t = threadIdx.x;
  int w = t >> 6, l = t & 63;
  int m16 = l & 15, g = l >> 4;
  int n0 = blockIdx.x * 64 + w * 16;
  int nrow = n0 + m16;

  f32x4v acc[8];
  // ---- Phase B: x3 = relu(z3 @ Wc3 + bc3), K=64 ----
#pragma unroll
  for (int nb = 0; nb < 8; ++nb) {
    float bv = bc3[nb * 16 + m16];
    acc[nb] = (f32x4v){bv, bv, bv, bv};
  }
#pragma unroll
  for (int kb = 0; kb < 2; ++kb) {
    half8 a = *reinterpret_cast<const half8*>(z3h + (size_t)nrow * 64 + kb * 32 + g * 8);
#pragma unroll
    for (int nb = 0; nb < 8; ++nb) {
      half8 b = W3pk[(kb * 8 + nb) * 64 + l];
      acc[nb] = __builtin_amdgcn_mfma_f32_16x16x32_f16(a, b, acc[nb], 0, 0, 0);
    }
  }
#pragma unroll
  for (int nb = 0; nb < 8; ++nb)
#pragma unroll
    for (int r = 0; r < 4; ++r)
      sX3[w][g * 4 + r][nb * 16 + m16] = (_Float16)fmaxf(acc[nb][r], 0.0f);
  __syncthreads();

  // ---- Phase C: out = c0 + [x3|x2|x1] @ Acat, K=224 ----
  float rd = rdinv[nrow];
#pragma unroll
  for (int nb = 0; nb < 8; ++nb) {
    float cv = c0[nb * 16 + m16];
    acc[nb] = (f32x4v){cv, cv, cv, cv};
  }
#pragma unroll
  for (int kb = 0; kb < 7; ++kb) {
    half8 a;
    if (kb < 4)
      a = *reinterpret_cast<const half8*>(&sX3[w][m16][kb * 32 + g * 8]);
    else if (kb < 6)
      a = cvt8h(X2h + (size_t)nrow * 64 + (kb - 4) * 32 + g * 8, rd);
    else
      a = cvt8h(X1h + (size_t)nrow * 32 + g * 8, rd);
#pragma unroll
    for (int nb = 0; nb < 8; ++nb) {
      half8 b = Apk[(kb * 8 + nb) * 64 + l];
      acc[nb] = __builtin_amdgcn_mfma_f32_16x16x32_f16(a, b, acc[nb], 0, 0, 0);
    }
  }
#pragma unroll
  for (int nb = 0; nb < 8; ++nb)
#pragma unroll
    for (int r = 0; r < 4; ++r) {
      int n = n0 + g * 4 + r;
      if (n < NN) out[(size_t)n * 128 + nb * 16 + m16] = acc[nb][r];
    }
}

extern "C" void kernel_launch(void* const* d_in, const int* in_sizes, int n_in,
                              void* d_out, int out_size, void* d_ws, size_t ws_size,
                              hipStream_t stream) {
  const float* x   = (const float*)d_in[0];
  const int* ei    = (const int*)d_in[1];
  const int* srcv  = ei;
  const int* dstv  = ei + NE;
  const float* w1  = (const float*)d_in[2];
  const float* b1  = (const float*)d_in[3];
  const float* fw1 = (const float*)d_in[4];
  const float* fb1 = (const float*)d_in[5];
  const float* w2  = (const float*)d_in[6];
  const float* b2  = (const float*)d_in[7];
  const float* fw2 = (const float*)d_in[8];
  const float* fb2 = (const float*)d_in[9];
  const float* w3  = (const float*)d_in[10];
  const float* b3  = (const float*)d_in[11];
  const float* fw3 = (const float*)d_in[12];
  const float* fb3 = (const float*)d_in[13];
  const float* wd1 = (const float*)d_in[14];
  const float* bd1 = (const float*)d_in[15];
  const float* wd2 = (const float*)d_in[16];
  const float* bd2 = (const float*)d_in[17];
  const float* wd3 = (const float*)d_in[18];
  const float* bd3 = (const float*)d_in[19];
  const float* ws1 = (const float*)d_in[20];
  const float* bs1 = (const float*)d_in[21];
  const float* ws2 = (const float*)d_in[22];
  const float* bs2 = (const float*)d_in[23];
  const float* wf  = (const float*)d_in[24];
  const float* bf  = (const float*)d_in[25];

  float* fp = (float*)d_ws;
  float* dinv = fp;                         // 50176
  float* rdinv= dinv + 50176;               // 50176
  _Float16* h1h = (_Float16*)(rdinv + 50176);  // 50048*32 halves
  _Float16* x1h = h1h + 1601536;               // 50048*32 halves
  _Float16* x2h = x1h + 1601536;               // 50048*64 halves
  _Float16* z3h = x2h + 3203072;               // 50048*64 halves
  float* Wc2  = (float*)(z3h + 3203072);    // 2048
  float* Wc3  = Wc2 + 2048;                 // 8192
  float* bc1  = Wc3 + 8192;                 // 64
  float* bc2  = bc1 + 64;                   // 64
  float* bc3  = bc2 + 64;                   // 128
  float* G    = bc3 + 128;                  // 16384
  float* Hm   = G + 16384;                  // 16384
  float* A3   = Hm + 16384;                 // 16384 } Acat = A3|A2|A1 [224][128]
  float* A2   = A3 + 16384;                 // 8192  }
  float* A1   = A2 + 8192;                  // 4096  }
  float* c0   = A1 + 4096;                  // 256
  _Float16* W3pk = (_Float16*)(c0 + 256);   // 8192 halves
  _Float16* Apk  = W3pk + 8192;             // 28672 halves
  _Float16* W1pk = Apk + 28672;             // 4096 halves
  unsigned int* epk2 = (unsigned int*)(W1pk + 4096);         // NBLK*CAP u32
  unsigned short* esrc = (unsigned short*)(epk2 + NBLK * CAP); // NBLK*CAP u16
  int* ip     = (int*)(esrc + NBLK * CAP);  // 4B aligned (NBLK*CAP even)
  int* row_start = ip;                      // 50176 (NN+1 used)
  int* bend   = row_start + 50176;          // 256
  int* bcur   = bend + 256;                 // 256

  float* outp = (float*)d_out;

  // ---- CSR build (padded buckets: no histogram, no scan) ----
  hipMemsetAsync(bcur, 0, NBLK * sizeof(int), stream);
  k_A<<<NBLK + 105 + 1, 256, 0, stream>>>(srcv, dstv, bcur, epk2,
                                          wd3, wf, w2, fw2, w3, fw3, b1, fw1, fb1,
                                          b2, fb2, b3, fb3, G, Wc2, Wc3, bc1, bc2, bc3,
                                          w1, W1pk);
  k_B<<<NBLK + 80, 256, 0, stream>>>(epk2, bcur, row_start, bend, dinv, rdinv, esrc,
                                     wd2, G, ws2, Hm, A1);
  // ---- layer-1 MFMA + A32c0 ----
  k_C<<<NG1 + 97, 256, 0, stream>>>(x, (const half8*)W1pk, dinv, h1h,
                                    wd1, ws1, Hm, G, wf, bd1, bs1, bd2, bs2, bd3, bf,
                                    A3, A2, c0);
  // ---- fuse1 + B-frag pack ----
  k_D<<<NF1 + 18, 256, 0, stream>>>(h1h, esrc, row_start, bend, dinv, fw1, bc1, x1h,
                                    Wc3, A3 /*Acat*/, W3pk, Apk);
  k_fuse2<<<NN / 8, 256, 0, stream>>>(x1h, esrc, row_start, bend, dinv, Wc2, bc2, x2h);
  k_gath64<<<NN / 4, 256, 0, stream>>>(x2h, esrc, row_start, bend, dinv, z3h);
  k_decode<<<(NN + 63) / 64, 256, 0, stream>>>(z3h, x2h, x1h, rdinv, (const half8*)W3pk,
                                               (const half8*)Apk, bc3, c0, outp);
}